// Round 1
// baseline (2869.848 us; speedup 1.0000x reference)
//
#include <hip/hip_runtime.h>
#include <math.h>

#define DEV __device__ __forceinline__

static const int N_LOW = 5000, N_HIGH = 50000, E_LH = 200000, E_HH = 400000;
static const int E2 = E_HH + N_HIGH; // 450000 with self loops

DEV float lrelu(float v) { return v >= 0.f ? v : 0.2f * v; }
DEV unsigned ordf(float f) {
    unsigned u = __float_as_uint(f);
    return (u & 0x80000000u) ? ~u : (u | 0x80000000u);
}
DEV float deord(unsigned o) {
    return (o & 0x80000000u) ? __uint_as_float(o & 0x7FFFFFFFu) : __uint_as_float(~o);
}

// ---------------- GEMM: C[M,N] = A[M,K] @ B[K,N] + bias, optional relu -----
// 64x64 tile, BK=16, 256 threads, 4x4 outputs/thread.
template <bool RELU>
__global__ __launch_bounds__(256) void gemm_bias(
    const float* __restrict__ A, const float* __restrict__ B,
    const float* __restrict__ bias, float* __restrict__ C,
    int M, int K, int N) {
    __shared__ float As[64][17];
    __shared__ float Bs[16][64];
    const int tid = threadIdx.x;
    const int tx = tid & 15, ty = tid >> 4;
    const int bm = blockIdx.y * 64, bn = blockIdx.x * 64;
    float acc[4][4] = {};
    for (int k0 = 0; k0 < K; k0 += 16) {
#pragma unroll
        for (int i = 0; i < 4; i++) {
            int e = tid + i * 256;
            int rr = e >> 4, kk = e & 15;
            int r = bm + rr, k = k0 + kk;
            As[rr][kk] = (r < M && k < K) ? A[(size_t)r * K + k] : 0.f;
        }
#pragma unroll
        for (int i = 0; i < 4; i++) {
            int e = tid + i * 256;
            int rr = e >> 6, cc = e & 63;
            int k = k0 + rr, c = bn + cc;
            Bs[rr][cc] = (k < K && c < N) ? B[(size_t)k * N + c] : 0.f;
        }
        __syncthreads();
#pragma unroll
        for (int kk = 0; kk < 16; kk++) {
            float a[4], b[4];
#pragma unroll
            for (int i = 0; i < 4; i++) a[i] = As[ty * 4 + i][kk];
#pragma unroll
            for (int j = 0; j < 4; j++) b[j] = Bs[kk][tx * 4 + j];
#pragma unroll
            for (int i = 0; i < 4; i++)
#pragma unroll
                for (int j = 0; j < 4; j++)
                    acc[i][j] = fmaf(a[i], b[j], acc[i][j]);
        }
        __syncthreads();
    }
#pragma unroll
    for (int i = 0; i < 4; i++) {
        int r = bm + ty * 4 + i;
        if (r >= M) continue;
#pragma unroll
        for (int j = 0; j < 4; j++) {
            int c = bn + tx * 4 + j;
            if (c >= N) continue;
            float v = acc[i][j] + bias[c];
            if (RELU) v = fmaxf(v, 0.f);
            C[(size_t)r * N + c] = v;
        }
    }
}

// ------------- edge logits: one wave per edge, 64 lanes over H*C -----------
template <int H, int C>
__global__ __launch_bounds__(256) void edge_logits(
    const float* __restrict__ hl, const float* __restrict__ hr,
    const int* __restrict__ src, const int* __restrict__ dst,
    const float* __restrict__ att, float* __restrict__ logit,
    unsigned* __restrict__ mord, int E) {
    const int HC = H * C;
    const int KP = HC / 64;
    int w = blockIdx.x * (blockDim.x >> 6) + (threadIdx.x >> 6);
    int l = threadIdx.x & 63;
    if (w >= E) return;
    int s = src[w], d = dst[w];
    float acc[KP];
#pragma unroll
    for (int k = 0; k < KP; k++) {
        int e = k * 64 + l;
        float z = lrelu(hl[(size_t)s * HC + e] + hr[(size_t)d * HC + e]);
        acc[k] = z * att[e];
    }
#pragma unroll
    for (int k = 0; k < KP; k++)
#pragma unroll
        for (int m = 1; m < 64; m <<= 1)
            acc[k] += __shfl_xor(acc[k], m, 64);
    if (l == 0) {
#pragma unroll
        for (int h = 0; h < H; h++) {
            float v = 0.f;
#pragma unroll
            for (int k = 0; k < KP; k++)
                if ((k * 64) / C == h) v += acc[k];
            logit[(size_t)w * H + h] = v;
            atomicMax(&mord[(size_t)d * H + h], ordf(v));
        }
    }
}

// ------------- exp(logit - max) and per-dst-per-head sums -----------------
__global__ __launch_bounds__(256) void edge_expsum(
    float* __restrict__ logit, const int* __restrict__ dst,
    const unsigned* __restrict__ mord, float* __restrict__ ssum,
    int E, int H) {
    int i = blockIdx.x * blockDim.x + threadIdx.x;
    if (i >= E * H) return;
    int e = i / H, h = i - e * H;
    int d = dst[e];
    float m = deord(mord[d * H + h]);
    float ex = expf(logit[i] - m);
    logit[i] = ex;
    atomicAdd(&ssum[d * H + h], ex);
}

// ------------- weighted message aggregation (atomics) ----------------------
template <int H, int C>
__global__ __launch_bounds__(256) void edge_aggregate(
    const float* __restrict__ hl, const float* __restrict__ ex,
    const float* __restrict__ ssum, const int* __restrict__ src,
    const int* __restrict__ dst, float* __restrict__ out, int E) {
    const int HC = H * C;
    const int KP = HC / 64;
    int w = blockIdx.x * (blockDim.x >> 6) + (threadIdx.x >> 6);
    int l = threadIdx.x & 63;
    if (w >= E) return;
    int s = src[w], d = dst[w];
    float alpha[H];
#pragma unroll
    for (int h = 0; h < H; h++)
        alpha[h] = ex[(size_t)w * H + h] / (ssum[(size_t)d * H + h] + 1e-16f);
#pragma unroll
    for (int k = 0; k < KP; k++) {
        int e = k * 64 + l;
        int h = (k * 64) / C;
        atomicAdd(&out[(size_t)d * HC + e], hl[(size_t)s * HC + e] * alpha[h]);
    }
}

__global__ __launch_bounds__(256) void count_dst(const int* __restrict__ dst,
                                                 float* __restrict__ cnt, int E) {
    for (int i = blockIdx.x * blockDim.x + threadIdx.x; i < E;
         i += gridDim.x * blockDim.x)
        atomicAdd(&cnt[dst[i]], 1.f);
}

__global__ __launch_bounds__(256) void finalize_mean_bias(
    float* __restrict__ out, const float* __restrict__ cnt,
    const float* __restrict__ bias, int N, int HC) {
    size_t total = (size_t)N * HC;
    for (size_t i = (size_t)blockIdx.x * blockDim.x + threadIdx.x; i < total;
         i += (size_t)gridDim.x * blockDim.x) {
        int n = (int)(i / HC), c = (int)(i % HC);
        out[i] = out[i] / fmaxf(cnt[n], 1.f) + bias[c];
    }
}

// x[N][257]: col 0 = zstd, cols 1..256 = enc/cnt + bias
__global__ __launch_bounds__(256) void concat_zstd_enc(
    const float* __restrict__ zstd, const float* __restrict__ enc,
    const float* __restrict__ cnt, const float* __restrict__ bias,
    float* __restrict__ x, int N) {
    size_t total = (size_t)N * 257;
    for (size_t i = (size_t)blockIdx.x * blockDim.x + threadIdx.x; i < total;
         i += (size_t)gridDim.x * blockDim.x) {
        int n = (int)(i / 257), c = (int)(i % 257);
        x[i] = (c == 0) ? zstd[n]
                        : enc[(size_t)n * 256 + (c - 1)] / fmaxf(cnt[n], 1.f) + bias[c - 1];
    }
}

__global__ __launch_bounds__(256) void build_edges(
    const int* __restrict__ si, const int* __restrict__ di,
    int* __restrict__ src2, int* __restrict__ dst2, int Ehh, int N) {
    int total = Ehh + N;
    for (int i = blockIdx.x * blockDim.x + threadIdx.x; i < total;
         i += gridDim.x * blockDim.x) {
        if (i < Ehh) { src2[i] = si[i]; dst2[i] = di[i]; }
        else { src2[i] = i - Ehh; dst2[i] = i - Ehh; }
    }
}

// one block per feature column
__global__ __launch_bounds__(256) void bn_stats(const float* __restrict__ x, int N,
                                                int F, float* __restrict__ mean,
                                                float* __restrict__ istd) {
    __shared__ float s1[256], s2[256];
    int f = blockIdx.x;
    float a = 0.f, b = 0.f;
    for (int i = threadIdx.x; i < N; i += 256) {
        float v = x[(size_t)i * F + f];
        a += v; b += v * v;
    }
    s1[threadIdx.x] = a; s2[threadIdx.x] = b;
    __syncthreads();
    for (int s = 128; s > 0; s >>= 1) {
        if (threadIdx.x < s) {
            s1[threadIdx.x] += s1[threadIdx.x + s];
            s2[threadIdx.x] += s2[threadIdx.x + s];
        }
        __syncthreads();
    }
    if (threadIdx.x == 0) {
        float mu = s1[0] / N;
        float var = s2[0] / N - mu * mu;
        mean[f] = mu;
        istd[f] = rsqrtf(fmaxf(var, 0.f) + 1e-5f);
    }
}

template <bool RELU>
__global__ __launch_bounds__(256) void bn_apply(
    float* __restrict__ x, const float* __restrict__ mean,
    const float* __restrict__ istd, const float* __restrict__ g,
    const float* __restrict__ b, size_t total, int F) {
    for (size_t i = (size_t)blockIdx.x * blockDim.x + threadIdx.x; i < total;
         i += (size_t)gridDim.x * blockDim.x) {
        int f = (int)(i % F);
        float v = (x[i] - mean[f]) * istd[f] * g[f] + b[f];
        if (RELU) v = fmaxf(v, 0.f);
        x[i] = v;
    }
}

// y[i] = dot64(hid[i], W2) + b2
__global__ __launch_bounds__(256) void dot_w2(const float* __restrict__ hid,
                                              const float* __restrict__ W2,
                                              const float* __restrict__ b2,
                                              float* __restrict__ y, int N) {
    int w = blockIdx.x * (blockDim.x >> 6) + (threadIdx.x >> 6);
    int l = threadIdx.x & 63;
    if (w >= N) return;
    float v = hid[(size_t)w * 64 + l] * W2[l];
#pragma unroll
    for (int m = 1; m < 64; m <<= 1) v += __shfl_xor(v, m, 64);
    if (l == 0) y[w] = v + b2[0];
}

// ---------------------------------------------------------------------------
extern "C" void kernel_launch(void* const* d_in, const int* in_sizes, int n_in,
                              void* d_out, int out_size, void* d_ws, size_t ws_size,
                              hipStream_t stream) {
    const float* xl   = (const float*)d_in[0];
    const float* xh   = (const float*)d_in[1];
    const float* zstd = (const float*)d_in[2];
    const int* si_lh  = (const int*)d_in[3];
    const int* di_lh  = (const int*)d_in[4];
    const int* si_hh  = (const int*)d_in[5];
    const int* di_hh  = (const int*)d_in[6];
    int a = 7;
    const float *d_Wl = (const float*)d_in[a++], *d_bl = (const float*)d_in[a++],
                *d_Wr = (const float*)d_in[a++], *d_br = (const float*)d_in[a++],
                *d_att = (const float*)d_in[a++], *d_b = (const float*)d_in[a++];
    const float *p1_Wl = (const float*)d_in[a++], *p1_bl = (const float*)d_in[a++],
                *p1_Wr = (const float*)d_in[a++], *p1_br = (const float*)d_in[a++],
                *p1_att = (const float*)d_in[a++], *p1_b = (const float*)d_in[a++];
    const float *p2_Wl = (const float*)d_in[a++], *p2_bl = (const float*)d_in[a++],
                *p2_Wr = (const float*)d_in[a++], *p2_br = (const float*)d_in[a++],
                *p2_att = (const float*)d_in[a++], *p2_b = (const float*)d_in[a++];
    const float *p3_Wl = (const float*)d_in[a++], *p3_bl = (const float*)d_in[a++],
                *p3_Wr = (const float*)d_in[a++], *p3_br = (const float*)d_in[a++],
                *p3_att = (const float*)d_in[a++], *p3_b = (const float*)d_in[a++];
    const float *bn0_g = (const float*)d_in[a++], *bn0_b = (const float*)d_in[a++],
                *bn1_g = (const float*)d_in[a++], *bn1_b = (const float*)d_in[a++],
                *bn2_g = (const float*)d_in[a++], *bn2_b = (const float*)d_in[a++],
                *bn3_g = (const float*)d_in[a++], *bn3_b = (const float*)d_in[a++];
    const float *pr_W1 = (const float*)d_in[a++], *pr_b1 = (const float*)d_in[a++],
                *pr_W2 = (const float*)d_in[a++], *pr_b2 = (const float*)d_in[a++];
    float* y = (float*)d_out;

    const int N = N_HIGH;
    // ---- workspace layout (floats) ----
    float* ws = (float*)d_ws;
    float* xA   = ws;                 // 50000*257
    float* xB   = xA + (size_t)N * 257;   // 50000*256
    float* hl   = xB + (size_t)N * 256;   // 50000*256
    float* hr   = hl + (size_t)N * 256;   // 50000*256
    float* elog = hr + (size_t)N * 256;   // 450000*4
    unsigned* mord = (unsigned*)(elog + (size_t)E2 * 4); // 200000
    float* ssum = (float*)mord + (size_t)N * 4;          // 200000
    float* cntd = ssum + (size_t)N * 4;                  // 50000
    float* cnth = cntd + N;                              // 50000
    int* src2 = (int*)(cnth + N);                        // 450000
    int* dst2 = src2 + E2;                               // 450000
    float* bnm = (float*)(dst2 + E2);                    // 257
    float* bni = bnm + 257;                              // 257
    size_t need = (size_t)((bni + 257) - ws) * sizeof(float);
    if (ws_size < need) return; // insufficient scratch; cannot proceed

    dim3 blk(256);
    auto wgrid = [](int E) { return dim3((E + 3) / 4); };   // 4 waves/block
    auto egrid = [](size_t total) {
        size_t g = (total + 255) / 256;
        return dim3((unsigned)(g > 16384 ? 16384 : g));
    };

    // ===================== d layer (low -> high, H=1, C=256) ================
    gemm_bias<false><<<dim3(4, (N_LOW + 63) / 64), blk, 0, stream>>>(xl, d_Wl, d_bl, hl, N_LOW, 125, 256);
    gemm_bias<false><<<dim3(4, (N + 63) / 64), blk, 0, stream>>>(xh, d_Wr, d_br, hr, N, 1, 256);
    hipMemsetAsync(mord, 0, (size_t)N * sizeof(unsigned), stream);
    hipMemsetAsync(ssum, 0, (size_t)N * sizeof(float), stream);
    edge_logits<1, 256><<<wgrid(E_LH), blk, 0, stream>>>(hl, hr, si_lh, di_lh, d_att, elog, mord, E_LH);
    edge_expsum<<<dim3((E_LH + 255) / 256), blk, 0, stream>>>(elog, di_lh, mord, ssum, E_LH, 1);
    hipMemsetAsync(xB, 0, (size_t)N * 256 * sizeof(float), stream);
    hipMemsetAsync(cntd, 0, (size_t)N * sizeof(float), stream);
    count_dst<<<egrid(E_LH), blk, 0, stream>>>(di_lh, cntd, E_LH);
    edge_aggregate<1, 256><<<wgrid(E_LH), blk, 0, stream>>>(hl, elog, ssum, si_lh, di_lh, xB, E_LH);
    concat_zstd_enc<<<egrid((size_t)N * 257), blk, 0, stream>>>(zstd, xB, cntd, d_b, xA, N);

    // ===================== edges with self loops ============================
    build_edges<<<egrid(E2), blk, 0, stream>>>(si_hh, di_hh, src2, dst2, E_HH, N);
    hipMemsetAsync(cnth, 0, (size_t)N * sizeof(float), stream);
    count_dst<<<egrid(E2), blk, 0, stream>>>(dst2, cnth, E2);

    // ===================== bn0 ==============================================
    bn_stats<<<dim3(257), blk, 0, stream>>>(xA, N, 257, bnm, bni);
    bn_apply<false><<<egrid((size_t)N * 257), blk, 0, stream>>>(xA, bnm, bni, bn0_g, bn0_b, (size_t)N * 257, 257);

    // ===================== p1 (H=4, C=64) ===================================
    gemm_bias<false><<<dim3(4, (N + 63) / 64), blk, 0, stream>>>(xA, p1_Wl, p1_bl, hl, N, 257, 256);
    gemm_bias<false><<<dim3(4, (N + 63) / 64), blk, 0, stream>>>(xA, p1_Wr, p1_br, hr, N, 257, 256);
    hipMemsetAsync(mord, 0, (size_t)N * 4 * sizeof(unsigned), stream);
    hipMemsetAsync(ssum, 0, (size_t)N * 4 * sizeof(float), stream);
    edge_logits<4, 64><<<wgrid(E2), blk, 0, stream>>>(hl, hr, src2, dst2, p1_att, elog, mord, E2);
    edge_expsum<<<dim3((E2 * 4 + 255) / 256), blk, 0, stream>>>(elog, dst2, mord, ssum, E2, 4);
    hipMemsetAsync(xB, 0, (size_t)N * 256 * sizeof(float), stream);
    edge_aggregate<4, 64><<<wgrid(E2), blk, 0, stream>>>(hl, elog, ssum, src2, dst2, xB, E2);
    finalize_mean_bias<<<egrid((size_t)N * 256), blk, 0, stream>>>(xB, cnth, p1_b, N, 256);
    bn_stats<<<dim3(256), blk, 0, stream>>>(xB, N, 256, bnm, bni);
    bn_apply<true><<<egrid((size_t)N * 256), blk, 0, stream>>>(xB, bnm, bni, bn1_g, bn1_b, (size_t)N * 256, 256);

    // ===================== p2 (H=4, C=64) ===================================
    gemm_bias<false><<<dim3(4, (N + 63) / 64), blk, 0, stream>>>(xB, p2_Wl, p2_bl, hl, N, 256, 256);
    gemm_bias<false><<<dim3(4, (N + 63) / 64), blk, 0, stream>>>(xB, p2_Wr, p2_br, hr, N, 256, 256);
    hipMemsetAsync(mord, 0, (size_t)N * 4 * sizeof(unsigned), stream);
    hipMemsetAsync(ssum, 0, (size_t)N * 4 * sizeof(float), stream);
    edge_logits<4, 64><<<wgrid(E2), blk, 0, stream>>>(hl, hr, src2, dst2, p2_att, elog, mord, E2);
    edge_expsum<<<dim3((E2 * 4 + 255) / 256), blk, 0, stream>>>(elog, dst2, mord, ssum, E2, 4);
    hipMemsetAsync(xA, 0, (size_t)N * 256 * sizeof(float), stream); // reuse xA as [N][256]
    edge_aggregate<4, 64><<<wgrid(E2), blk, 0, stream>>>(hl, elog, ssum, src2, dst2, xA, E2);
    finalize_mean_bias<<<egrid((size_t)N * 256), blk, 0, stream>>>(xA, cnth, p2_b, N, 256);
    bn_stats<<<dim3(256), blk, 0, stream>>>(xA, N, 256, bnm, bni);
    bn_apply<true><<<egrid((size_t)N * 256), blk, 0, stream>>>(xA, bnm, bni, bn2_g, bn2_b, (size_t)N * 256, 256);

    // ===================== p3 (H=1, C=64) ===================================
    gemm_bias<false><<<dim3(1, (N + 63) / 64), blk, 0, stream>>>(xA, p3_Wl, p3_bl, hl, N, 256, 64);
    gemm_bias<false><<<dim3(1, (N + 63) / 64), blk, 0, stream>>>(xA, p3_Wr, p3_br, hr, N, 256, 64);
    hipMemsetAsync(mord, 0, (size_t)N * sizeof(unsigned), stream);
    hipMemsetAsync(ssum, 0, (size_t)N * sizeof(float), stream);
    edge_logits<1, 64><<<wgrid(E2), blk, 0, stream>>>(hl, hr, src2, dst2, p3_att, elog, mord, E2);
    edge_expsum<<<dim3((E2 + 255) / 256), blk, 0, stream>>>(elog, dst2, mord, ssum, E2, 1);
    hipMemsetAsync(xB, 0, (size_t)N * 64 * sizeof(float), stream); // reuse xB as [N][64]
    edge_aggregate<1, 64><<<wgrid(E2), blk, 0, stream>>>(hl, elog, ssum, src2, dst2, xB, E2);
    finalize_mean_bias<<<egrid((size_t)N * 64), blk, 0, stream>>>(xB, cnth, p3_b, N, 64);
    bn_stats<<<dim3(64), blk, 0, stream>>>(xB, N, 64, bnm, bni);
    bn_apply<true><<<egrid((size_t)N * 64), blk, 0, stream>>>(xB, bnm, bni, bn3_g, bn3_b, (size_t)N * 64, 64);

    // ===================== predictor MLP ====================================
    gemm_bias<true><<<dim3(1, (N + 63) / 64), blk, 0, stream>>>(xB, pr_W1, pr_b1, hl, N, 64, 64);
    dot_w2<<<wgrid(N), blk, 0, stream>>>(hl, pr_W2, pr_b2, y, N);
}

// Round 2
// 1751.528 us; speedup vs baseline: 1.6385x; 1.6385x over previous
//
#include <hip/hip_runtime.h>
#include <math.h>

#define DEV __device__ __forceinline__

static const int N_LOW = 5000, N_HIGH = 50000, E_LH = 200000, E_HH = 400000;
static const int E2 = E_HH + N_HIGH; // 450000 with self loops

DEV float lrelu(float v) { return v >= 0.f ? v : 0.2f * v; }

// ---------------- GEMM: C[M,N] = A[M,K] @ B[K,N] + bias, optional relu -----
// 64x64 tile, BK=16, 256 threads, 4x4 outputs/thread.
template <bool RELU>
__global__ __launch_bounds__(256) void gemm_bias(
    const float* __restrict__ A, const float* __restrict__ B,
    const float* __restrict__ bias, float* __restrict__ C,
    int M, int K, int N) {
    __shared__ float As[64][17];
    __shared__ float Bs[16][64];
    const int tid = threadIdx.x;
    const int tx = tid & 15, ty = tid >> 4;
    const int bm = blockIdx.y * 64, bn = blockIdx.x * 64;
    float acc[4][4] = {};
    for (int k0 = 0; k0 < K; k0 += 16) {
#pragma unroll
        for (int i = 0; i < 4; i++) {
            int e = tid + i * 256;
            int rr = e >> 4, kk = e & 15;
            int r = bm + rr, k = k0 + kk;
            As[rr][kk] = (r < M && k < K) ? A[(size_t)r * K + k] : 0.f;
        }
#pragma unroll
        for (int i = 0; i < 4; i++) {
            int e = tid + i * 256;
            int rr = e >> 6, cc = e & 63;
            int k = k0 + rr, c = bn + cc;
            Bs[rr][cc] = (k < K && c < N) ? B[(size_t)k * N + c] : 0.f;
        }
        __syncthreads();
#pragma unroll
        for (int kk = 0; kk < 16; kk++) {
            float a[4], b[4];
#pragma unroll
            for (int i = 0; i < 4; i++) a[i] = As[ty * 4 + i][kk];
#pragma unroll
            for (int j = 0; j < 4; j++) b[j] = Bs[kk][tx * 4 + j];
#pragma unroll
            for (int i = 0; i < 4; i++)
#pragma unroll
                for (int j = 0; j < 4; j++)
                    acc[i][j] = fmaf(a[i], b[j], acc[i][j]);
        }
        __syncthreads();
    }
#pragma unroll
    for (int i = 0; i < 4; i++) {
        int r = bm + ty * 4 + i;
        if (r >= M) continue;
#pragma unroll
        for (int j = 0; j < 4; j++) {
            int c = bn + tx * 4 + j;
            if (c >= N) continue;
            float v = acc[i][j] + bias[c];
            if (RELU) v = fmaxf(v, 0.f);
            C[(size_t)r * N + c] = v;
        }
    }
}

// ------------------- CSR build: histogram / scan / scatter -----------------
__global__ __launch_bounds__(256) void hist_dst(const int* __restrict__ dst,
                                                int* __restrict__ cnt, int E) {
    for (int i = blockIdx.x * blockDim.x + threadIdx.x; i < E;
         i += gridDim.x * blockDim.x)
        atomicAdd(&cnt[dst[i]], 1);
}

// single-block exclusive scan of cnt[0..N) -> off[0..N], off[N] = total
__global__ __launch_bounds__(256) void exscan(const int* __restrict__ cnt,
                                              int* __restrict__ off, int N) {
    __shared__ int s[256];
    const int tid = threadIdx.x;
    const int chunk = (N + 255) / 256;
    int lo = tid * chunk, hi = lo + chunk;
    if (hi > N) hi = N;
    int sum = 0;
    for (int i = lo; i < hi; i++) sum += cnt[i];
    s[tid] = sum;
    __syncthreads();
    for (int step = 1; step < 256; step <<= 1) {
        int v = (tid >= step) ? s[tid - step] : 0;
        __syncthreads();
        s[tid] += v;
        __syncthreads();
    }
    int run = (tid > 0) ? s[tid - 1] : 0;
    for (int i = lo; i < hi; i++) {
        off[i] = run;
        run += cnt[i];
    }
    if (tid == 255) off[N] = run;
}

__global__ __launch_bounds__(256) void scatter_csr(const int* __restrict__ src,
                                                   const int* __restrict__ dst,
                                                   int* __restrict__ cur,
                                                   int* __restrict__ csr, int E) {
    for (int i = blockIdx.x * blockDim.x + threadIdx.x; i < E;
         i += gridDim.x * blockDim.x) {
        int p = atomicAdd(&cur[dst[i]], 1);
        csr[p] = src[i];
    }
}

__global__ __launch_bounds__(256) void build_edges(
    const int* __restrict__ si, const int* __restrict__ di,
    int* __restrict__ src2, int* __restrict__ dst2, int Ehh, int N) {
    int total = Ehh + N;
    for (int i = blockIdx.x * blockDim.x + threadIdx.x; i < total;
         i += gridDim.x * blockDim.x) {
        if (i < Ehh) { src2[i] = si[i]; dst2[i] = di[i]; }
        else { src2[i] = i - Ehh; dst2[i] = i - Ehh; }
    }
}

// ---------- fused GATv2: logit + online softmax + mean-aggregate + bias ----
// one wave per dst node; lane l owns feature elems [l*VPL, l*VPL+VPL)
template <int H, int C>
__global__ __launch_bounds__(256) void gat_gather(
    const float* __restrict__ hl, const float* __restrict__ hr,
    const int* __restrict__ rowptr, const int* __restrict__ csr_src,
    const float* __restrict__ att, const float* __restrict__ bias,
    float* __restrict__ out, int outStride, int outOfs, int Ndst) {
    constexpr int HC = H * C;
    constexpr int VPL = HC / 64;       // values per lane
    constexpr int LPH = C / VPL;       // lanes per head (group size)
    int w = blockIdx.x * (blockDim.x >> 6) + (threadIdx.x >> 6);
    if (w >= Ndst) return;
    const int l = threadIdx.x & 63;

    float hrv[VPL], attv[VPL];
    if constexpr (VPL == 4) {
        float4 t = *reinterpret_cast<const float4*>(hr + (size_t)w * HC + l * 4);
        hrv[0] = t.x; hrv[1] = t.y; hrv[2] = t.z; hrv[3] = t.w;
        float4 u = *reinterpret_cast<const float4*>(att + l * 4);
        attv[0] = u.x; attv[1] = u.y; attv[2] = u.z; attv[3] = u.w;
    } else {
#pragma unroll
        for (int j = 0; j < VPL; j++) {
            hrv[j] = hr[(size_t)w * HC + l * VPL + j];
            attv[j] = att[l * VPL + j];
        }
    }

    const int e0 = rowptr[w], e1 = rowptr[w + 1];
    float m = -3.4e38f, s = 0.f;
    float acc[VPL] = {};
    for (int e = e0; e < e1; e++) {
        int sv = csr_src[e];
        float hlv[VPL];
        if constexpr (VPL == 4) {
            float4 t = *reinterpret_cast<const float4*>(hl + (size_t)sv * HC + l * 4);
            hlv[0] = t.x; hlv[1] = t.y; hlv[2] = t.z; hlv[3] = t.w;
        } else {
#pragma unroll
            for (int j = 0; j < VPL; j++) hlv[j] = hl[(size_t)sv * HC + l * VPL + j];
        }
        float v = 0.f;
#pragma unroll
        for (int j = 0; j < VPL; j++) v += lrelu(hlv[j] + hrv[j]) * attv[j];
#pragma unroll
        for (int t = 1; t < LPH; t <<= 1) v += __shfl_xor(v, t, 64);
        float nm = fmaxf(m, v);
        float sc = __expf(m - nm);   // 0 on first edge (m = -3.4e38)
        float p = __expf(v - nm);
        s = s * sc + p;
#pragma unroll
        for (int j = 0; j < VPL; j++) acc[j] = fmaf(acc[j], sc, p * hlv[j]);
        m = nm;
    }
    float inv = 1.f / (s + 1e-16f);
    float dnorm = inv / fmaxf((float)(e1 - e0), 1.f);
#pragma unroll
    for (int j = 0; j < VPL; j++)
        out[(size_t)w * outStride + outOfs + l * VPL + j] =
            acc[j] * dnorm + bias[l * VPL + j];
}

__global__ __launch_bounds__(256) void copy_col0(const float* __restrict__ zstd,
                                                 float* __restrict__ xA, int N) {
    for (int i = blockIdx.x * blockDim.x + threadIdx.x; i < N;
         i += gridDim.x * blockDim.x)
        xA[(size_t)i * 257] = zstd[i];
}

// one block per feature column
__global__ __launch_bounds__(256) void bn_stats(const float* __restrict__ x, int N,
                                                int F, float* __restrict__ mean,
                                                float* __restrict__ istd) {
    __shared__ float s1[256], s2[256];
    int f = blockIdx.x;
    float a = 0.f, b = 0.f;
    for (int i = threadIdx.x; i < N; i += 256) {
        float v = x[(size_t)i * F + f];
        a += v; b += v * v;
    }
    s1[threadIdx.x] = a; s2[threadIdx.x] = b;
    __syncthreads();
    for (int s = 128; s > 0; s >>= 1) {
        if (threadIdx.x < s) {
            s1[threadIdx.x] += s1[threadIdx.x + s];
            s2[threadIdx.x] += s2[threadIdx.x + s];
        }
        __syncthreads();
    }
    if (threadIdx.x == 0) {
        float mu = s1[0] / N;
        float var = s2[0] / N - mu * mu;
        mean[f] = mu;
        istd[f] = rsqrtf(fmaxf(var, 0.f) + 1e-5f);
    }
}

template <bool RELU>
__global__ __launch_bounds__(256) void bn_apply(
    float* __restrict__ x, const float* __restrict__ mean,
    const float* __restrict__ istd, const float* __restrict__ g,
    const float* __restrict__ b, size_t total, int F) {
    for (size_t i = (size_t)blockIdx.x * blockDim.x + threadIdx.x; i < total;
         i += (size_t)gridDim.x * blockDim.x) {
        int f = (int)(i % F);
        float v = (x[i] - mean[f]) * istd[f] * g[f] + b[f];
        if (RELU) v = fmaxf(v, 0.f);
        x[i] = v;
    }
}

// y[i] = dot64(hid[i], W2) + b2
__global__ __launch_bounds__(256) void dot_w2(const float* __restrict__ hid,
                                              const float* __restrict__ W2,
                                              const float* __restrict__ b2,
                                              float* __restrict__ y, int N) {
    int w = blockIdx.x * (blockDim.x >> 6) + (threadIdx.x >> 6);
    int l = threadIdx.x & 63;
    if (w >= N) return;
    float v = hid[(size_t)w * 64 + l] * W2[l];
#pragma unroll
    for (int m = 1; m < 64; m <<= 1) v += __shfl_xor(v, m, 64);
    if (l == 0) y[w] = v + b2[0];
}

// ---------------------------------------------------------------------------
extern "C" void kernel_launch(void* const* d_in, const int* in_sizes, int n_in,
                              void* d_out, int out_size, void* d_ws, size_t ws_size,
                              hipStream_t stream) {
    const float* xl   = (const float*)d_in[0];
    const float* xh   = (const float*)d_in[1];
    const float* zstd = (const float*)d_in[2];
    const int* si_lh  = (const int*)d_in[3];
    const int* di_lh  = (const int*)d_in[4];
    const int* si_hh  = (const int*)d_in[5];
    const int* di_hh  = (const int*)d_in[6];
    int a = 7;
    const float *d_Wl = (const float*)d_in[a++], *d_bl = (const float*)d_in[a++],
                *d_Wr = (const float*)d_in[a++], *d_br = (const float*)d_in[a++],
                *d_att = (const float*)d_in[a++], *d_b = (const float*)d_in[a++];
    const float *p1_Wl = (const float*)d_in[a++], *p1_bl = (const float*)d_in[a++],
                *p1_Wr = (const float*)d_in[a++], *p1_br = (const float*)d_in[a++],
                *p1_att = (const float*)d_in[a++], *p1_b = (const float*)d_in[a++];
    const float *p2_Wl = (const float*)d_in[a++], *p2_bl = (const float*)d_in[a++],
                *p2_Wr = (const float*)d_in[a++], *p2_br = (const float*)d_in[a++],
                *p2_att = (const float*)d_in[a++], *p2_b = (const float*)d_in[a++];
    const float *p3_Wl = (const float*)d_in[a++], *p3_bl = (const float*)d_in[a++],
                *p3_Wr = (const float*)d_in[a++], *p3_br = (const float*)d_in[a++],
                *p3_att = (const float*)d_in[a++], *p3_b = (const float*)d_in[a++];
    const float *bn0_g = (const float*)d_in[a++], *bn0_b = (const float*)d_in[a++],
                *bn1_g = (const float*)d_in[a++], *bn1_b = (const float*)d_in[a++],
                *bn2_g = (const float*)d_in[a++], *bn2_b = (const float*)d_in[a++],
                *bn3_g = (const float*)d_in[a++], *bn3_b = (const float*)d_in[a++];
    const float *pr_W1 = (const float*)d_in[a++], *pr_b1 = (const float*)d_in[a++],
                *pr_W2 = (const float*)d_in[a++], *pr_b2 = (const float*)d_in[a++];
    float* y = (float*)d_out;

    const int N = N_HIGH;
    // ---- workspace layout ----
    float* ws = (float*)d_ws;
    float* xA = ws;                           // 50000*257
    float* xB = xA + (size_t)N * 257;         // 50000*256
    float* hl = xB + (size_t)N * 256;         // 50000*256 (16B-aligned)
    float* hr = hl + (size_t)N * 256;         // 50000*256 (16B-aligned)
    float* bnm = hr + (size_t)N * 256;        // 257
    float* bni = bnm + 257;                   // 257
    int* itmp   = (int*)(bni + 257);          // 50000 (histogram)
    int* rp_lh  = itmp + N;                   // 50001
    int* rp_hh  = rp_lh + (N + 1);            // 50001
    int* cur    = rp_hh + (N + 1);            // 50000
    int* csr_lh = cur + N;                    // 200000
    int* csr_hh = csr_lh + E_LH;              // 450000
    int* src2   = csr_hh + E2;                // 450000
    int* dst2   = src2 + E2;                  // 450000
    size_t need = (size_t)((char*)(dst2 + E2) - (char*)ws);
    if (ws_size < need) return;

    dim3 blk(256);
    auto wgrid = [](int E) { return dim3((E + 3) / 4); };   // 4 waves/block
    auto egrid = [](size_t total) {
        size_t g = (total + 255) / 256;
        return dim3((unsigned)(g > 2048 ? 2048 : g));
    };

    // ===================== CSR builds =======================================
    // lh edges (by di_lh)
    hipMemsetAsync(itmp, 0, (size_t)N * sizeof(int), stream);
    hist_dst<<<egrid(E_LH), blk, 0, stream>>>(di_lh, itmp, E_LH);
    exscan<<<dim3(1), blk, 0, stream>>>(itmp, rp_lh, N);
    hipMemcpyAsync(cur, rp_lh, (size_t)N * sizeof(int), hipMemcpyDeviceToDevice, stream);
    scatter_csr<<<egrid(E_LH), blk, 0, stream>>>(si_lh, di_lh, cur, csr_lh, E_LH);
    // hh edges + self loops (by dst2)
    build_edges<<<egrid(E2), blk, 0, stream>>>(si_hh, di_hh, src2, dst2, E_HH, N);
    hipMemsetAsync(itmp, 0, (size_t)N * sizeof(int), stream);
    hist_dst<<<egrid(E2), blk, 0, stream>>>(dst2, itmp, E2);
    exscan<<<dim3(1), blk, 0, stream>>>(itmp, rp_hh, N);
    hipMemcpyAsync(cur, rp_hh, (size_t)N * sizeof(int), hipMemcpyDeviceToDevice, stream);
    scatter_csr<<<egrid(E2), blk, 0, stream>>>(src2, dst2, cur, csr_hh, E2);

    // ===================== d layer (low -> high, H=1, C=256) ================
    gemm_bias<false><<<dim3(4, (N_LOW + 63) / 64), blk, 0, stream>>>(xl, d_Wl, d_bl, hl, N_LOW, 125, 256);
    gemm_bias<false><<<dim3(4, (N + 63) / 64), blk, 0, stream>>>(xh, d_Wr, d_br, hr, N, 1, 256);
    gat_gather<1, 256><<<wgrid(N), blk, 0, stream>>>(hl, hr, rp_lh, csr_lh, d_att, d_b, xA, 257, 1, N);
    copy_col0<<<egrid(N), blk, 0, stream>>>(zstd, xA, N);

    // ===================== bn0 ==============================================
    bn_stats<<<dim3(257), blk, 0, stream>>>(xA, N, 257, bnm, bni);
    bn_apply<false><<<egrid((size_t)N * 257), blk, 0, stream>>>(xA, bnm, bni, bn0_g, bn0_b, (size_t)N * 257, 257);

    // ===================== p1 (H=4, C=64) ===================================
    gemm_bias<false><<<dim3(4, (N + 63) / 64), blk, 0, stream>>>(xA, p1_Wl, p1_bl, hl, N, 257, 256);
    gemm_bias<false><<<dim3(4, (N + 63) / 64), blk, 0, stream>>>(xA, p1_Wr, p1_br, hr, N, 257, 256);
    gat_gather<4, 64><<<wgrid(N), blk, 0, stream>>>(hl, hr, rp_hh, csr_hh, p1_att, p1_b, xB, 256, 0, N);
    bn_stats<<<dim3(256), blk, 0, stream>>>(xB, N, 256, bnm, bni);
    bn_apply<true><<<egrid((size_t)N * 256), blk, 0, stream>>>(xB, bnm, bni, bn1_g, bn1_b, (size_t)N * 256, 256);

    // ===================== p2 (H=4, C=64) ===================================
    gemm_bias<false><<<dim3(4, (N + 63) / 64), blk, 0, stream>>>(xB, p2_Wl, p2_bl, hl, N, 256, 256);
    gemm_bias<false><<<dim3(4, (N + 63) / 64), blk, 0, stream>>>(xB, p2_Wr, p2_br, hr, N, 256, 256);
    gat_gather<4, 64><<<wgrid(N), blk, 0, stream>>>(hl, hr, rp_hh, csr_hh, p2_att, p2_b, xA, 256, 0, N);
    bn_stats<<<dim3(256), blk, 0, stream>>>(xA, N, 256, bnm, bni);
    bn_apply<true><<<egrid((size_t)N * 256), blk, 0, stream>>>(xA, bnm, bni, bn2_g, bn2_b, (size_t)N * 256, 256);

    // ===================== p3 (H=1, C=64) ===================================
    gemm_bias<false><<<dim3(1, (N + 63) / 64), blk, 0, stream>>>(xA, p3_Wl, p3_bl, hl, N, 256, 64);
    gemm_bias<false><<<dim3(1, (N + 63) / 64), blk, 0, stream>>>(xA, p3_Wr, p3_br, hr, N, 256, 64);
    gat_gather<1, 64><<<wgrid(N), blk, 0, stream>>>(hl, hr, rp_hh, csr_hh, p3_att, p3_b, xB, 64, 0, N);
    bn_stats<<<dim3(64), blk, 0, stream>>>(xB, N, 64, bnm, bni);
    bn_apply<true><<<egrid((size_t)N * 64), blk, 0, stream>>>(xB, bnm, bni, bn3_g, bn3_b, (size_t)N * 64, 64);

    // ===================== predictor MLP ====================================
    gemm_bias<true><<<dim3(1, (N + 63) / 64), blk, 0, stream>>>(xB, pr_W1, pr_b1, hl, N, 64, 64);
    dot_w2<<<wgrid(N), blk, 0, stream>>>(hl, pr_W2, pr_b2, y, N);
}

// Round 3
// 1179.190 us; speedup vs baseline: 2.4337x; 1.4854x over previous
//
#include <hip/hip_runtime.h>
#include <math.h>

#define DEV __device__ __forceinline__

static const int N_LOW = 5000, N_HIGH = 50000, E_LH = 200000, E_HH = 400000;
static const int E2 = E_HH + N_HIGH; // 450000 with self loops

typedef __attribute__((ext_vector_type(8))) short bf16x8;
typedef __attribute__((ext_vector_type(4))) float f32x4;

DEV float lrelu(float v) { return v >= 0.f ? v : 0.2f * v; }
DEV short f2bf(float v) {            // round-to-nearest-even f32 -> bf16
    unsigned u = __float_as_uint(v);
    u += 0x7FFFu + ((u >> 16) & 1u);
    return (short)(u >> 16);
}

// =================== MFMA GEMM on fragment-ordered operands =================
// Af: [nmt][nkt][64 lanes][8 bf16]  lane l, j -> A[mt*16 + (l&15)][kt*32 + (l>>4)*8 + j]
// Bf: [nnt][nkt][64 lanes][8 bf16]  lane l, j -> B[kt*32 + (l>>4)*8 + j][nt*16 + (l&15)]
// Block: 4 waves; wave w covers rows [bm + w*32, +32) x cols [bn, +64).
template <bool RELU>
__global__ __launch_bounds__(256) void gemm_mfma(
    const bf16x8* __restrict__ Af, const bf16x8* __restrict__ Bf,
    const float* __restrict__ bias, float* __restrict__ C,
    int M, int N, int nkt) {
    const int l = threadIdx.x & 63;
    const int w = threadIdx.x >> 6;
    const int nt0 = blockIdx.x * 4;
    const int mt0 = blockIdx.y * 8 + w * 2;
    f32x4 acc[2][4];
#pragma unroll
    for (int i = 0; i < 2; i++)
#pragma unroll
        for (int j = 0; j < 4; j++) acc[i][j] = (f32x4){0.f, 0.f, 0.f, 0.f};
    const bf16x8* a0p = Af + (size_t)mt0 * nkt * 64 + l;
    const bf16x8* a1p = a0p + (size_t)nkt * 64;
    const bf16x8* bp = Bf + (size_t)nt0 * nkt * 64 + l;
    for (int kt = 0; kt < nkt; kt++) {
        bf16x8 a0 = a0p[kt * 64];
        bf16x8 a1 = a1p[kt * 64];
        bf16x8 b0 = bp[kt * 64];
        bf16x8 b1 = bp[(size_t)(nkt + kt) * 64];
        bf16x8 b2 = bp[(size_t)(2 * nkt + kt) * 64];
        bf16x8 b3 = bp[(size_t)(3 * nkt + kt) * 64];
        acc[0][0] = __builtin_amdgcn_mfma_f32_16x16x32_bf16(a0, b0, acc[0][0], 0, 0, 0);
        acc[0][1] = __builtin_amdgcn_mfma_f32_16x16x32_bf16(a0, b1, acc[0][1], 0, 0, 0);
        acc[0][2] = __builtin_amdgcn_mfma_f32_16x16x32_bf16(a0, b2, acc[0][2], 0, 0, 0);
        acc[0][3] = __builtin_amdgcn_mfma_f32_16x16x32_bf16(a0, b3, acc[0][3], 0, 0, 0);
        acc[1][0] = __builtin_amdgcn_mfma_f32_16x16x32_bf16(a1, b0, acc[1][0], 0, 0, 0);
        acc[1][1] = __builtin_amdgcn_mfma_f32_16x16x32_bf16(a1, b1, acc[1][1], 0, 0, 0);
        acc[1][2] = __builtin_amdgcn_mfma_f32_16x16x32_bf16(a1, b2, acc[1][2], 0, 0, 0);
        acc[1][3] = __builtin_amdgcn_mfma_f32_16x16x32_bf16(a1, b3, acc[1][3], 0, 0, 0);
    }
    const int colb = nt0 * 16 + (l & 15);
    const int rsub = (l >> 4) * 4;
#pragma unroll
    for (int mi = 0; mi < 2; mi++) {
        int rowb = (mt0 + mi) * 16 + rsub;
#pragma unroll
        for (int r = 0; r < 4; r++) {
            int row = rowb + r;
            if (row >= M) continue;
#pragma unroll
            for (int n = 0; n < 4; n++) {
                int col = colb + n * 16;
                float v = acc[mi][n][r] + bias[col];
                if (RELU) v = fmaxf(v, 0.f);
                C[(size_t)row * N + col] = v;
            }
        }
    }
}

// --------- BN-apply + (relu) + bf16 cast into fragment-ordered A -----------
template <bool RELU>
__global__ __launch_bounds__(256) void bn_frag(
    const float* __restrict__ x, int Nrows, int F,
    const float* __restrict__ mean, const float* __restrict__ istd,
    const float* __restrict__ g, const float* __restrict__ b,
    bf16x8* __restrict__ Af, int nmt, int nkt) {
    int total = nmt * nkt * 64;
    for (int idx = blockIdx.x * blockDim.x + threadIdx.x; idx < total;
         idx += gridDim.x * blockDim.x) {
        int mt = idx / (nkt * 64);
        int rem = idx - mt * (nkt * 64);
        int kt = rem >> 6, l = rem & 63;
        int row = mt * 16 + (l & 15);
        int colb = kt * 32 + (l >> 4) * 8;
        bf16x8 o;
#pragma unroll
        for (int j = 0; j < 8; j++) {
            int col = colb + j;
            float v = 0.f;
            if (row < Nrows && col < F) {
                v = (x[(size_t)row * F + col] - mean[col]) * istd[col] * g[col] + b[col];
                if (RELU) v = fmaxf(v, 0.f);
            }
            o[j] = f2bf(v);
        }
        Af[idx] = o;
    }
}

// --------- plain cast (xl) into fragment-ordered A, zero-padded -----------
__global__ __launch_bounds__(256) void cast_frag(
    const float* __restrict__ x, int Nrows, int F,
    bf16x8* __restrict__ Af, int nmt, int nkt) {
    int total = nmt * nkt * 64;
    for (int idx = blockIdx.x * blockDim.x + threadIdx.x; idx < total;
         idx += gridDim.x * blockDim.x) {
        int mt = idx / (nkt * 64);
        int rem = idx - mt * (nkt * 64);
        int kt = rem >> 6, l = rem & 63;
        int row = mt * 16 + (l & 15);
        int colb = kt * 32 + (l >> 4) * 8;
        bf16x8 o;
#pragma unroll
        for (int j = 0; j < 8; j++) {
            int col = colb + j;
            o[j] = (row < Nrows && col < F) ? f2bf(x[(size_t)row * F + col]) : (short)0;
        }
        Af[idx] = o;
    }
}

// --------- weight [K][N] -> fragment-ordered B, zero-padded ----------------
__global__ __launch_bounds__(256) void wt_frag(
    const float* __restrict__ W, int K, int N,
    bf16x8* __restrict__ Bf, int nnt, int nkt) {
    int total = nnt * nkt * 64;
    for (int idx = blockIdx.x * blockDim.x + threadIdx.x; idx < total;
         idx += gridDim.x * blockDim.x) {
        int nt = idx / (nkt * 64);
        int rem = idx - nt * (nkt * 64);
        int kt = rem >> 6, l = rem & 63;
        int col = nt * 16 + (l & 15);
        int kb = kt * 32 + (l >> 4) * 8;
        bf16x8 o;
#pragma unroll
        for (int j = 0; j < 8; j++) {
            int k = kb + j;
            o[j] = (k < K && col < N) ? f2bf(W[(size_t)k * N + col]) : (short)0;
        }
        Bf[idx] = o;
    }
}

// --------- hr = xh * Wr + br  (K=1 outer product) --------------------------
__global__ __launch_bounds__(256) void outer_hr(
    const float* __restrict__ xh, const float* __restrict__ Wr,
    const float* __restrict__ br, float* __restrict__ hr, int N) {
    int total = N * 64;
    for (int i = blockIdx.x * blockDim.x + threadIdx.x; i < total;
         i += gridDim.x * blockDim.x) {
        int n = i >> 6, c = (i & 63) * 4;
        float x = xh[n];
        float4 w = *reinterpret_cast<const float4*>(Wr + c);
        float4 b = *reinterpret_cast<const float4*>(br + c);
        float4 o = {fmaf(x, w.x, b.x), fmaf(x, w.y, b.y),
                    fmaf(x, w.z, b.z), fmaf(x, w.w, b.w)};
        *reinterpret_cast<float4*>(hr + (size_t)n * 256 + c) = o;
    }
}

// ------------------- CSR build: histogram / scan / scatter -----------------
__global__ __launch_bounds__(256) void hist_dst(const int* __restrict__ dst,
                                                int* __restrict__ cnt, int E) {
    for (int i = blockIdx.x * blockDim.x + threadIdx.x; i < E;
         i += gridDim.x * blockDim.x)
        atomicAdd(&cnt[dst[i]], 1);
}

__global__ __launch_bounds__(256) void exscan(const int* __restrict__ cnt,
                                              int* __restrict__ off, int N) {
    __shared__ int s[256];
    const int tid = threadIdx.x;
    const int chunk = (N + 255) / 256;
    int lo = tid * chunk, hi = lo + chunk;
    if (hi > N) hi = N;
    int sum = 0;
    for (int i = lo; i < hi; i++) sum += cnt[i];
    s[tid] = sum;
    __syncthreads();
    for (int step = 1; step < 256; step <<= 1) {
        int v = (tid >= step) ? s[tid - step] : 0;
        __syncthreads();
        s[tid] += v;
        __syncthreads();
    }
    int run = (tid > 0) ? s[tid - 1] : 0;
    for (int i = lo; i < hi; i++) {
        off[i] = run;
        run += cnt[i];
    }
    if (tid == 255) off[N] = run;
}

__global__ __launch_bounds__(256) void scatter_csr(const int* __restrict__ src,
                                                   const int* __restrict__ dst,
                                                   int* __restrict__ cur,
                                                   int* __restrict__ csr, int E) {
    for (int i = blockIdx.x * blockDim.x + threadIdx.x; i < E;
         i += gridDim.x * blockDim.x) {
        int p = atomicAdd(&cur[dst[i]], 1);
        csr[p] = src[i];
    }
}

__global__ __launch_bounds__(256) void build_edges(
    const int* __restrict__ si, const int* __restrict__ di,
    int* __restrict__ src2, int* __restrict__ dst2, int Ehh, int N) {
    int total = Ehh + N;
    for (int i = blockIdx.x * blockDim.x + threadIdx.x; i < total;
         i += gridDim.x * blockDim.x) {
        if (i < Ehh) { src2[i] = si[i]; dst2[i] = di[i]; }
        else { src2[i] = i - Ehh; dst2[i] = i - Ehh; }
    }
}

// ---------- fused GATv2: logit + online softmax + mean-aggregate + bias ----
template <int H, int C>
__global__ __launch_bounds__(256) void gat_gather(
    const float* __restrict__ hl, const float* __restrict__ hr,
    const int* __restrict__ rowptr, const int* __restrict__ csr_src,
    const float* __restrict__ att, const float* __restrict__ bias,
    float* __restrict__ out, int outStride, int outOfs, int Ndst) {
    constexpr int HC = H * C;
    constexpr int VPL = HC / 64;
    constexpr int LPH = C / VPL;
    int w = blockIdx.x * (blockDim.x >> 6) + (threadIdx.x >> 6);
    if (w >= Ndst) return;
    const int l = threadIdx.x & 63;

    float hrv[VPL], attv[VPL];
    if constexpr (VPL == 4) {
        float4 t = *reinterpret_cast<const float4*>(hr + (size_t)w * HC + l * 4);
        hrv[0] = t.x; hrv[1] = t.y; hrv[2] = t.z; hrv[3] = t.w;
        float4 u = *reinterpret_cast<const float4*>(att + l * 4);
        attv[0] = u.x; attv[1] = u.y; attv[2] = u.z; attv[3] = u.w;
    } else {
#pragma unroll
        for (int j = 0; j < VPL; j++) {
            hrv[j] = hr[(size_t)w * HC + l * VPL + j];
            attv[j] = att[l * VPL + j];
        }
    }

    const int e0 = rowptr[w], e1 = rowptr[w + 1];
    float m = -3.4e38f, s = 0.f;
    float acc[VPL] = {};
    for (int e = e0; e < e1; e++) {
        int sv = csr_src[e];
        float hlv[VPL];
        if constexpr (VPL == 4) {
            float4 t = *reinterpret_cast<const float4*>(hl + (size_t)sv * HC + l * 4);
            hlv[0] = t.x; hlv[1] = t.y; hlv[2] = t.z; hlv[3] = t.w;
        } else {
#pragma unroll
            for (int j = 0; j < VPL; j++) hlv[j] = hl[(size_t)sv * HC + l * VPL + j];
        }
        float v = 0.f;
#pragma unroll
        for (int j = 0; j < VPL; j++) v += lrelu(hlv[j] + hrv[j]) * attv[j];
#pragma unroll
        for (int t = 1; t < LPH; t <<= 1) v += __shfl_xor(v, t, 64);
        float nm = fmaxf(m, v);
        float sc = __expf(m - nm);
        float p = __expf(v - nm);
        s = s * sc + p;
#pragma unroll
        for (int j = 0; j < VPL; j++) acc[j] = fmaf(acc[j], sc, p * hlv[j]);
        m = nm;
    }
    float inv = 1.f / (s + 1e-16f);
    float dnorm = inv / fmaxf((float)(e1 - e0), 1.f);
#pragma unroll
    for (int j = 0; j < VPL; j++)
        out[(size_t)w * outStride + outOfs + l * VPL + j] =
            acc[j] * dnorm + bias[l * VPL + j];
}

__global__ __launch_bounds__(256) void copy_col0(const float* __restrict__ zstd,
                                                 float* __restrict__ xA, int N) {
    for (int i = blockIdx.x * blockDim.x + threadIdx.x; i < N;
         i += gridDim.x * blockDim.x)
        xA[(size_t)i * 257] = zstd[i];
}

// one block per feature column
__global__ __launch_bounds__(256) void bn_stats(const float* __restrict__ x, int N,
                                                int F, float* __restrict__ mean,
                                                float* __restrict__ istd) {
    __shared__ float s1[256], s2[256];
    int f = blockIdx.x;
    float a = 0.f, b = 0.f;
    for (int i = threadIdx.x; i < N; i += 256) {
        float v = x[(size_t)i * F + f];
        a += v; b += v * v;
    }
    s1[threadIdx.x] = a; s2[threadIdx.x] = b;
    __syncthreads();
    for (int s = 128; s > 0; s >>= 1) {
        if (threadIdx.x < s) {
            s1[threadIdx.x] += s1[threadIdx.x + s];
            s2[threadIdx.x] += s2[threadIdx.x + s];
        }
        __syncthreads();
    }
    if (threadIdx.x == 0) {
        float mu = s1[0] / N;
        float var = s2[0] / N - mu * mu;
        mean[f] = mu;
        istd[f] = rsqrtf(fmaxf(var, 0.f) + 1e-5f);
    }
}

// y[i] = dot64(hid[i], W2) + b2
__global__ __launch_bounds__(256) void dot_w2(const float* __restrict__ hid,
                                              const float* __restrict__ W2,
                                              const float* __restrict__ b2,
                                              float* __restrict__ y, int N) {
    int w = blockIdx.x * (blockDim.x >> 6) + (threadIdx.x >> 6);
    int l = threadIdx.x & 63;
    if (w >= N) return;
    float v = hid[(size_t)w * 64 + l] * W2[l];
#pragma unroll
    for (int m = 1; m < 64; m <<= 1) v += __shfl_xor(v, m, 64);
    if (l == 0) y[w] = v + b2[0];
}

// ---------------------------------------------------------------------------
extern "C" void kernel_launch(void* const* d_in, const int* in_sizes, int n_in,
                              void* d_out, int out_size, void* d_ws, size_t ws_size,
                              hipStream_t stream) {
    const float* xl   = (const float*)d_in[0];
    const float* xh   = (const float*)d_in[1];
    const float* zstd = (const float*)d_in[2];
    const int* si_lh  = (const int*)d_in[3];
    const int* di_lh  = (const int*)d_in[4];
    const int* si_hh  = (const int*)d_in[5];
    const int* di_hh  = (const int*)d_in[6];
    int a = 7;
    const float *d_Wl = (const float*)d_in[a++], *d_bl = (const float*)d_in[a++],
                *d_Wr = (const float*)d_in[a++], *d_br = (const float*)d_in[a++],
                *d_att = (const float*)d_in[a++], *d_b = (const float*)d_in[a++];
    const float *p1_Wl = (const float*)d_in[a++], *p1_bl = (const float*)d_in[a++],
                *p1_Wr = (const float*)d_in[a++], *p1_br = (const float*)d_in[a++],
                *p1_att = (const float*)d_in[a++], *p1_b = (const float*)d_in[a++];
    const float *p2_Wl = (const float*)d_in[a++], *p2_bl = (const float*)d_in[a++],
                *p2_Wr = (const float*)d_in[a++], *p2_br = (const float*)d_in[a++],
                *p2_att = (const float*)d_in[a++], *p2_b = (const float*)d_in[a++];
    const float *p3_Wl = (const float*)d_in[a++], *p3_bl = (const float*)d_in[a++],
                *p3_Wr = (const float*)d_in[a++], *p3_br = (const float*)d_in[a++],
                *p3_att = (const float*)d_in[a++], *p3_b = (const float*)d_in[a++];
    const float *bn0_g = (const float*)d_in[a++], *bn0_b = (const float*)d_in[a++],
                *bn1_g = (const float*)d_in[a++], *bn1_b = (const float*)d_in[a++],
                *bn2_g = (const float*)d_in[a++], *bn2_b = (const float*)d_in[a++],
                *bn3_g = (const float*)d_in[a++], *bn3_b = (const float*)d_in[a++];
    const float *pr_W1 = (const float*)d_in[a++], *pr_b1 = (const float*)d_in[a++],
                *pr_W2 = (const float*)d_in[a++], *pr_b2 = (const float*)d_in[a++];
    float* y = (float*)d_out;

    const int N = N_HIGH;
    const int NMT = 3125;           // 50000/16
    // ---- workspace layout ----
    float* ws = (float*)d_ws;
    float* xA = ws;                           // 50000*257 f32 (also hosts Af)
    float* xB = xA + (size_t)N * 257;         // 50000*256 f32 (also hosts Af)
    float* hl = xB + (size_t)N * 256;         // 50000*256 f32
    float* hr = hl + (size_t)N * 256;         // 50000*256 f32
    bf16x8* xl_f = (bf16x8*)(hr + (size_t)N * 256);   // 320*4*64 frags
    bf16x8* wf_d   = xl_f + 320 * 4 * 64;     // 16*4*64
    bf16x8* wf_p1l = wf_d + 16 * 4 * 64;      // 16*9*64
    bf16x8* wf_p1r = wf_p1l + 16 * 9 * 64;
    bf16x8* wf_p2l = wf_p1r + 16 * 9 * 64;    // 16*8*64
    bf16x8* wf_p2r = wf_p2l + 16 * 8 * 64;
    bf16x8* wf_p3l = wf_p2r + 16 * 8 * 64;    // 4*8*64
    bf16x8* wf_p3r = wf_p3l + 4 * 8 * 64;
    bf16x8* wf_pr1 = wf_p3r + 4 * 8 * 64;     // 4*2*64
    float* bnm = (float*)(wf_pr1 + 4 * 2 * 64);  // 257
    float* bni = bnm + 257;                   // 257
    int* itmp   = (int*)(bni + 257);          // 50000
    int* rp_lh  = itmp + N;                   // 50001
    int* rp_hh  = rp_lh + (N + 1);            // 50001
    int* cur    = rp_hh + (N + 1);            // 50000
    int* csr_lh = cur + N;                    // 200000
    int* csr_hh = csr_lh + E_LH;              // 450000
    int* src2   = csr_hh + E2;                // 450000
    int* dst2   = src2 + E2;                  // 450000
    size_t need = (size_t)((char*)(dst2 + E2) - (char*)ws);
    if (ws_size < need) return;
    bf16x8* AfB = (bf16x8*)xB;   // A-frags overlaying xB (while xB dead)
    bf16x8* AfA = (bf16x8*)xA;   // A-frags overlaying xA (while xA dead)

    dim3 blk(256);
    auto wgrid = [](int E) { return dim3((E + 3) / 4); };
    auto egrid = [](size_t total) {
        size_t g = (total + 255) / 256;
        return dim3((unsigned)(g > 2048 ? 2048 : g));
    };

    // ===================== weight fragment transforms =======================
    wt_frag<<<dim3(16), blk, 0, stream>>>(d_Wl, 125, 256, wf_d, 16, 4);
    wt_frag<<<dim3(36), blk, 0, stream>>>(p1_Wl, 257, 256, wf_p1l, 16, 9);
    wt_frag<<<dim3(36), blk, 0, stream>>>(p1_Wr, 257, 256, wf_p1r, 16, 9);
    wt_frag<<<dim3(32), blk, 0, stream>>>(p2_Wl, 256, 256, wf_p2l, 16, 8);
    wt_frag<<<dim3(32), blk, 0, stream>>>(p2_Wr, 256, 256, wf_p2r, 16, 8);
    wt_frag<<<dim3(8),  blk, 0, stream>>>(p3_Wl, 256, 64, wf_p3l, 4, 8);
    wt_frag<<<dim3(8),  blk, 0, stream>>>(p3_Wr, 256, 64, wf_p3r, 4, 8);
    wt_frag<<<dim3(2),  blk, 0, stream>>>(pr_W1, 64, 64, wf_pr1, 4, 2);
    cast_frag<<<dim3(320), blk, 0, stream>>>(xl, N_LOW, 125, xl_f, 320, 4);

    // ===================== CSR builds =======================================
    hipMemsetAsync(itmp, 0, (size_t)N * sizeof(int), stream);
    hist_dst<<<egrid(E_LH), blk, 0, stream>>>(di_lh, itmp, E_LH);
    exscan<<<dim3(1), blk, 0, stream>>>(itmp, rp_lh, N);
    hipMemcpyAsync(cur, rp_lh, (size_t)N * sizeof(int), hipMemcpyDeviceToDevice, stream);
    scatter_csr<<<egrid(E_LH), blk, 0, stream>>>(si_lh, di_lh, cur, csr_lh, E_LH);
    build_edges<<<egrid(E2), blk, 0, stream>>>(si_hh, di_hh, src2, dst2, E_HH, N);
    hipMemsetAsync(itmp, 0, (size_t)N * sizeof(int), stream);
    hist_dst<<<egrid(E2), blk, 0, stream>>>(dst2, itmp, E2);
    exscan<<<dim3(1), blk, 0, stream>>>(itmp, rp_hh, N);
    hipMemcpyAsync(cur, rp_hh, (size_t)N * sizeof(int), hipMemcpyDeviceToDevice, stream);
    scatter_csr<<<egrid(E2), blk, 0, stream>>>(src2, dst2, cur, csr_hh, E2);

    // ===================== d layer (low -> high, H=1, C=256) ================
    gemm_mfma<false><<<dim3(4, 40), blk, 0, stream>>>(xl_f, wf_d, d_bl, hl, N_LOW, 256, 4);
    outer_hr<<<egrid((size_t)N * 64), blk, 0, stream>>>(xh, d_Wr, d_br, hr, N);
    gat_gather<1, 256><<<wgrid(N), blk, 0, stream>>>(hl, hr, rp_lh, csr_lh, d_att, d_b, xA, 257, 1, N);
    copy_col0<<<egrid(N), blk, 0, stream>>>(zstd, xA, N);

    // ===================== bn0 + frag cast ==================================
    bn_stats<<<dim3(257), blk, 0, stream>>>(xA, N, 257, bnm, bni);
    bn_frag<false><<<dim3(2048), blk, 0, stream>>>(xA, N, 257, bnm, bni, bn0_g, bn0_b, AfB, NMT, 9);

    // ===================== p1 (H=4, C=64) ===================================
    gemm_mfma<false><<<dim3(4, 391), blk, 0, stream>>>(AfB, wf_p1l, p1_bl, hl, N, 256, 9);
    gemm_mfma<false><<<dim3(4, 391), blk, 0, stream>>>(AfB, wf_p1r, p1_br, hr, N, 256, 9);
    gat_gather<4, 64><<<wgrid(N), blk, 0, stream>>>(hl, hr, rp_hh, csr_hh, p1_att, p1_b, xB, 256, 0, N);
    bn_stats<<<dim3(256), blk, 0, stream>>>(xB, N, 256, bnm, bni);
    bn_frag<true><<<dim3(2048), blk, 0, stream>>>(xB, N, 256, bnm, bni, bn1_g, bn1_b, AfA, NMT, 8);

    // ===================== p2 (H=4, C=64) ===================================
    gemm_mfma<false><<<dim3(4, 391), blk, 0, stream>>>(AfA, wf_p2l, p2_bl, hl, N, 256, 8);
    gemm_mfma<false><<<dim3(4, 391), blk, 0, stream>>>(AfA, wf_p2r, p2_br, hr, N, 256, 8);
    gat_gather<4, 64><<<wgrid(N), blk, 0, stream>>>(hl, hr, rp_hh, csr_hh, p2_att, p2_b, xA, 256, 0, N);
    bn_stats<<<dim3(256), blk, 0, stream>>>(xA, N, 256, bnm, bni);
    bn_frag<true><<<dim3(2048), blk, 0, stream>>>(xA, N, 256, bnm, bni, bn2_g, bn2_b, AfB, NMT, 8);

    // ===================== p3 (H=1, C=64) ===================================
    gemm_mfma<false><<<dim3(1, 391), blk, 0, stream>>>(AfB, wf_p3l, p3_bl, hl, N, 64, 8);
    gemm_mfma<false><<<dim3(1, 391), blk, 0, stream>>>(AfB, wf_p3r, p3_br, hr, N, 64, 8);
    gat_gather<1, 64><<<wgrid(N), blk, 0, stream>>>(hl, hr, rp_hh, csr_hh, p3_att, p3_b, xB, 64, 0, N);
    bn_stats<<<dim3(64), blk, 0, stream>>>(xB, N, 64, bnm, bni);
    bn_frag<true><<<dim3(2048), blk, 0, stream>>>(xB, N, 64, bnm, bni, bn3_g, bn3_b, AfA, NMT, 2);

    // ===================== predictor MLP ====================================
    gemm_mfma<true><<<dim3(1, 391), blk, 0, stream>>>(AfA, wf_pr1, pr_b1, hl, N, 64, 2);
    dot_w2<<<wgrid(N), blk, 0, stream>>>(hl, pr_W2, pr_b2, y, N);
}

// Round 4
// 1055.724 us; speedup vs baseline: 2.7184x; 1.1169x over previous
//
#include <hip/hip_runtime.h>
#include <math.h>

#define DEV __device__ __forceinline__

static const int N_LOW = 5000, N_HIGH = 50000, E_LH = 200000, E_HH = 400000;
static const int E2 = E_HH + N_HIGH; // 450000 with self loops

typedef __attribute__((ext_vector_type(8))) short bf16x8;
typedef __attribute__((ext_vector_type(4))) float f32x4;

DEV float lrelu(float v) { return v >= 0.f ? v : 0.2f * v; }
DEV short f2bf(float v) {            // round-to-nearest-even f32 -> bf16
    unsigned u = __float_as_uint(v);
    u += 0x7FFFu + ((u >> 16) & 1u);
    return (short)(u >> 16);
}

// =================== MFMA GEMM on fragment-ordered operands =================
// Af: [nmt][nkt][64 lanes][8 bf16]  lane l, j -> A[mt*16 + (l&15)][kt*32 + (l>>4)*8 + j]
// Bf: [nnt][nkt][64 lanes][8 bf16]  lane l, j -> B[kt*32 + (l>>4)*8 + j][nt*16 + (l&15)]
// Block: 4 waves; wave w covers rows [bm + w*32, +32) x cols [bn, +64).
template <bool RELU>
__global__ __launch_bounds__(256) void gemm_mfma(
    const bf16x8* __restrict__ Af, const bf16x8* __restrict__ Bf,
    const float* __restrict__ bias, float* __restrict__ C,
    int M, int N, int nkt) {
    const int l = threadIdx.x & 63;
    const int w = threadIdx.x >> 6;
    const int nt0 = blockIdx.x * 4;
    const int mt0 = blockIdx.y * 8 + w * 2;
    f32x4 acc[2][4];
#pragma unroll
    for (int i = 0; i < 2; i++)
#pragma unroll
        for (int j = 0; j < 4; j++) acc[i][j] = (f32x4){0.f, 0.f, 0.f, 0.f};
    const bf16x8* a0p = Af + (size_t)mt0 * nkt * 64 + l;
    const bf16x8* a1p = a0p + (size_t)nkt * 64;
    const bf16x8* bp = Bf + (size_t)nt0 * nkt * 64 + l;
    for (int kt = 0; kt < nkt; kt++) {
        bf16x8 a0 = a0p[kt * 64];
        bf16x8 a1 = a1p[kt * 64];
        bf16x8 b0 = bp[kt * 64];
        bf16x8 b1 = bp[(size_t)(nkt + kt) * 64];
        bf16x8 b2 = bp[(size_t)(2 * nkt + kt) * 64];
        bf16x8 b3 = bp[(size_t)(3 * nkt + kt) * 64];
        acc[0][0] = __builtin_amdgcn_mfma_f32_16x16x32_bf16(a0, b0, acc[0][0], 0, 0, 0);
        acc[0][1] = __builtin_amdgcn_mfma_f32_16x16x32_bf16(a0, b1, acc[0][1], 0, 0, 0);
        acc[0][2] = __builtin_amdgcn_mfma_f32_16x16x32_bf16(a0, b2, acc[0][2], 0, 0, 0);
        acc[0][3] = __builtin_amdgcn_mfma_f32_16x16x32_bf16(a0, b3, acc[0][3], 0, 0, 0);
        acc[1][0] = __builtin_amdgcn_mfma_f32_16x16x32_bf16(a1, b0, acc[1][0], 0, 0, 0);
        acc[1][1] = __builtin_amdgcn_mfma_f32_16x16x32_bf16(a1, b1, acc[1][1], 0, 0, 0);
        acc[1][2] = __builtin_amdgcn_mfma_f32_16x16x32_bf16(a1, b2, acc[1][2], 0, 0, 0);
        acc[1][3] = __builtin_amdgcn_mfma_f32_16x16x32_bf16(a1, b3, acc[1][3], 0, 0, 0);
    }
    const int colb = nt0 * 16 + (l & 15);
    const int rsub = (l >> 4) * 4;
#pragma unroll
    for (int mi = 0; mi < 2; mi++) {
        int rowb = (mt0 + mi) * 16 + rsub;
#pragma unroll
        for (int r = 0; r < 4; r++) {
            int row = rowb + r;
            if (row >= M) continue;
#pragma unroll
            for (int n = 0; n < 4; n++) {
                int col = colb + n * 16;
                float v = acc[mi][n][r] + bias[col];
                if (RELU) v = fmaxf(v, 0.f);
                C[(size_t)row * N + col] = v;
            }
        }
    }
}

// --------- BN-apply + (relu) + bf16 cast into fragment-ordered A -----------
template <bool RELU>
__global__ __launch_bounds__(256) void bn_frag(
    const float* __restrict__ x, int Nrows, int F,
    const float* __restrict__ mean, const float* __restrict__ istd,
    const float* __restrict__ g, const float* __restrict__ b,
    bf16x8* __restrict__ Af, int nmt, int nkt) {
    int total = nmt * nkt * 64;
    for (int idx = blockIdx.x * blockDim.x + threadIdx.x; idx < total;
         idx += gridDim.x * blockDim.x) {
        int mt = idx / (nkt * 64);
        int rem = idx - mt * (nkt * 64);
        int kt = rem >> 6, l = rem & 63;
        int row = mt * 16 + (l & 15);
        int colb = kt * 32 + (l >> 4) * 8;
        bf16x8 o;
#pragma unroll
        for (int j = 0; j < 8; j++) {
            int col = colb + j;
            float v = 0.f;
            if (row < Nrows && col < F) {
                v = (x[(size_t)row * F + col] - mean[col]) * istd[col] * g[col] + b[col];
                if (RELU) v = fmaxf(v, 0.f);
            }
            o[j] = f2bf(v);
        }
        Af[idx] = o;
    }
}

// --------- plain cast (xl) into fragment-ordered A, zero-padded -----------
__global__ __launch_bounds__(256) void cast_frag(
    const float* __restrict__ x, int Nrows, int F,
    bf16x8* __restrict__ Af, int nmt, int nkt) {
    int total = nmt * nkt * 64;
    for (int idx = blockIdx.x * blockDim.x + threadIdx.x; idx < total;
         idx += gridDim.x * blockDim.x) {
        int mt = idx / (nkt * 64);
        int rem = idx - mt * (nkt * 64);
        int kt = rem >> 6, l = rem & 63;
        int row = mt * 16 + (l & 15);
        int colb = kt * 32 + (l >> 4) * 8;
        bf16x8 o;
#pragma unroll
        for (int j = 0; j < 8; j++) {
            int col = colb + j;
            o[j] = (row < Nrows && col < F) ? f2bf(x[(size_t)row * F + col]) : (short)0;
        }
        Af[idx] = o;
    }
}

// --------- weight [K][N] -> fragment-ordered B, zero-padded ----------------
__global__ __launch_bounds__(256) void wt_frag(
    const float* __restrict__ W, int K, int N,
    bf16x8* __restrict__ Bf, int nnt, int nkt) {
    int total = nnt * nkt * 64;
    for (int idx = blockIdx.x * blockDim.x + threadIdx.x; idx < total;
         idx += gridDim.x * blockDim.x) {
        int nt = idx / (nkt * 64);
        int rem = idx - nt * (nkt * 64);
        int kt = rem >> 6, l = rem & 63;
        int col = nt * 16 + (l & 15);
        int kb = kt * 32 + (l >> 4) * 8;
        bf16x8 o;
#pragma unroll
        for (int j = 0; j < 8; j++) {
            int k = kb + j;
            o[j] = (k < K && col < N) ? f2bf(W[(size_t)k * N + col]) : (short)0;
        }
        Bf[idx] = o;
    }
}

// --------- hr = xh * Wr + br  (K=1 outer product) --------------------------
__global__ __launch_bounds__(256) void outer_hr(
    const float* __restrict__ xh, const float* __restrict__ Wr,
    const float* __restrict__ br, float* __restrict__ hr, int N) {
    int total = N * 64;
    for (int i = blockIdx.x * blockDim.x + threadIdx.x; i < total;
         i += gridDim.x * blockDim.x) {
        int n = i >> 6, c = (i & 63) * 4;
        float x = xh[n];
        float4 w = *reinterpret_cast<const float4*>(Wr + c);
        float4 b = *reinterpret_cast<const float4*>(br + c);
        float4 o = {fmaf(x, w.x, b.x), fmaf(x, w.y, b.y),
                    fmaf(x, w.z, b.z), fmaf(x, w.w, b.w)};
        *reinterpret_cast<float4*>(hr + (size_t)n * 256 + c) = o;
    }
}

// ------------------- CSR build: histogram / scan / scatter -----------------
__global__ __launch_bounds__(256) void hist_dst(const int* __restrict__ dst,
                                                int* __restrict__ cnt, int E) {
    for (int i = blockIdx.x * blockDim.x + threadIdx.x; i < E;
         i += gridDim.x * blockDim.x)
        atomicAdd(&cnt[dst[i]], 1);
}

__global__ __launch_bounds__(256) void exscan(const int* __restrict__ cnt,
                                              int* __restrict__ off, int N) {
    __shared__ int s[256];
    const int tid = threadIdx.x;
    const int chunk = (N + 255) / 256;
    int lo = tid * chunk, hi = lo + chunk;
    if (hi > N) hi = N;
    int sum = 0;
    for (int i = lo; i < hi; i++) sum += cnt[i];
    s[tid] = sum;
    __syncthreads();
    for (int step = 1; step < 256; step <<= 1) {
        int v = (tid >= step) ? s[tid - step] : 0;
        __syncthreads();
        s[tid] += v;
        __syncthreads();
    }
    int run = (tid > 0) ? s[tid - 1] : 0;
    for (int i = lo; i < hi; i++) {
        off[i] = run;
        run += cnt[i];
    }
    if (tid == 255) off[N] = run;
}

__global__ __launch_bounds__(256) void scatter_csr(const int* __restrict__ src,
                                                   const int* __restrict__ dst,
                                                   int* __restrict__ cur,
                                                   int* __restrict__ csr, int E) {
    for (int i = blockIdx.x * blockDim.x + threadIdx.x; i < E;
         i += gridDim.x * blockDim.x) {
        int p = atomicAdd(&cur[dst[i]], 1);
        csr[p] = src[i];
    }
}

__global__ __launch_bounds__(256) void build_edges(
    const int* __restrict__ si, const int* __restrict__ di,
    int* __restrict__ src2, int* __restrict__ dst2, int Ehh, int N) {
    int total = Ehh + N;
    for (int i = blockIdx.x * blockDim.x + threadIdx.x; i < total;
         i += gridDim.x * blockDim.x) {
        if (i < Ehh) { src2[i] = si[i]; dst2[i] = di[i]; }
        else { src2[i] = i - Ehh; dst2[i] = i - Ehh; }
    }
}

// ---------- fused GATv2: logit + online softmax + mean-aggregate + bias ----
template <int H, int C>
__global__ __launch_bounds__(256) void gat_gather(
    const float* __restrict__ hl, const float* __restrict__ hr,
    const int* __restrict__ rowptr, const int* __restrict__ csr_src,
    const float* __restrict__ att, const float* __restrict__ bias,
    float* __restrict__ out, int outStride, int outOfs, int Ndst) {
    constexpr int HC = H * C;
    constexpr int VPL = HC / 64;
    constexpr int LPH = C / VPL;
    int w = blockIdx.x * (blockDim.x >> 6) + (threadIdx.x >> 6);
    if (w >= Ndst) return;
    const int l = threadIdx.x & 63;

    float hrv[VPL], attv[VPL];
    if constexpr (VPL == 4) {
        float4 t = *reinterpret_cast<const float4*>(hr + (size_t)w * HC + l * 4);
        hrv[0] = t.x; hrv[1] = t.y; hrv[2] = t.z; hrv[3] = t.w;
        float4 u = *reinterpret_cast<const float4*>(att + l * 4);
        attv[0] = u.x; attv[1] = u.y; attv[2] = u.z; attv[3] = u.w;
    } else {
#pragma unroll
        for (int j = 0; j < VPL; j++) {
            hrv[j] = hr[(size_t)w * HC + l * VPL + j];
            attv[j] = att[l * VPL + j];
        }
    }

    const int e0 = rowptr[w], e1 = rowptr[w + 1];
    float m = -3.4e38f, s = 0.f;
    float acc[VPL] = {};
    for (int e = e0; e < e1; e++) {
        int sv = csr_src[e];
        float hlv[VPL];
        if constexpr (VPL == 4) {
            float4 t = *reinterpret_cast<const float4*>(hl + (size_t)sv * HC + l * 4);
            hlv[0] = t.x; hlv[1] = t.y; hlv[2] = t.z; hlv[3] = t.w;
        } else {
#pragma unroll
            for (int j = 0; j < VPL; j++) hlv[j] = hl[(size_t)sv * HC + l * VPL + j];
        }
        float v = 0.f;
#pragma unroll
        for (int j = 0; j < VPL; j++) v += lrelu(hlv[j] + hrv[j]) * attv[j];
#pragma unroll
        for (int t = 1; t < LPH; t <<= 1) v += __shfl_xor(v, t, 64);
        float nm = fmaxf(m, v);
        float sc = __expf(m - nm);
        float p = __expf(v - nm);
        s = s * sc + p;
#pragma unroll
        for (int j = 0; j < VPL; j++) acc[j] = fmaf(acc[j], sc, p * hlv[j]);
        m = nm;
    }
    float inv = 1.f / (s + 1e-16f);
    float dnorm = inv / fmaxf((float)(e1 - e0), 1.f);
#pragma unroll
    for (int j = 0; j < VPL; j++)
        out[(size_t)w * outStride + outOfs + l * VPL + j] =
            acc[j] * dnorm + bias[l * VPL + j];
}

__global__ __launch_bounds__(256) void copy_col0(const float* __restrict__ zstd,
                                                 float* __restrict__ xA, int N) {
    for (int i = blockIdx.x * blockDim.x + threadIdx.x; i < N;
         i += gridDim.x * blockDim.x)
        xA[(size_t)i * 257] = zstd[i];
}

// ----------- BN stats, row-parallel: coalesced partial sums + atomics ------
// sums[0..F) = sum, sums[F..2F) = sumsq. Must be zeroed before launch.
__global__ __launch_bounds__(256) void bn_partial(
    const float* __restrict__ x, int Nrows, int F, float* __restrict__ sums) {
    const int t = threadIdx.x;
    if (F == 64) {
        int col = t & 63, rofs = t >> 6;       // 4 rows per block-iteration
        float s1 = 0.f, s2 = 0.f;
        for (int r0 = blockIdx.x * 8; r0 < Nrows; r0 += gridDim.x * 8) {
#pragma unroll
            for (int u = 0; u < 2; u++) {
                int r = r0 + u * 4 + rofs;
                if (r < Nrows) {
                    float v = x[(size_t)r * 64 + col];
                    s1 += v; s2 += v * v;
                }
            }
        }
        atomicAdd(&sums[col], s1);
        atomicAdd(&sums[64 + col], s2);
    } else {                                    // F in {256, 257}
        const bool extra = (F > 256) && (t < F - 256);
        float a1 = 0.f, a2 = 0.f, b1 = 0.f, b2 = 0.f;
        for (int r0 = blockIdx.x * 2; r0 < Nrows; r0 += gridDim.x * 2) {
#pragma unroll
            for (int u = 0; u < 2; u++) {
                int r = r0 + u;
                if (r < Nrows) {
                    const float* row = x + (size_t)r * F;
                    float v = row[t];
                    a1 += v; a2 += v * v;
                    if (extra) {
                        float q = row[t + 256];
                        b1 += q; b2 += q * q;
                    }
                }
            }
        }
        atomicAdd(&sums[t], a1);
        atomicAdd(&sums[F + t], a2);
        if (extra) {
            atomicAdd(&sums[t + 256], b1);
            atomicAdd(&sums[F + t + 256], b2);
        }
    }
}

__global__ __launch_bounds__(256) void bn_finalize(
    const float* __restrict__ sums, int Nrows, int F,
    float* __restrict__ mean, float* __restrict__ istd) {
    for (int t = threadIdx.x; t < F; t += 256) {
        float mu = sums[t] / Nrows;
        float var = sums[F + t] / Nrows - mu * mu;
        mean[t] = mu;
        istd[t] = rsqrtf(fmaxf(var, 0.f) + 1e-5f);
    }
}

// y[i] = dot64(hid[i], W2) + b2
__global__ __launch_bounds__(256) void dot_w2(const float* __restrict__ hid,
                                              const float* __restrict__ W2,
                                              const float* __restrict__ b2,
                                              float* __restrict__ y, int N) {
    int w = blockIdx.x * (blockDim.x >> 6) + (threadIdx.x >> 6);
    int l = threadIdx.x & 63;
    if (w >= N) return;
    float v = hid[(size_t)w * 64 + l] * W2[l];
#pragma unroll
    for (int m = 1; m < 64; m <<= 1) v += __shfl_xor(v, m, 64);
    if (l == 0) y[w] = v + b2[0];
}

// ---------------------------------------------------------------------------
extern "C" void kernel_launch(void* const* d_in, const int* in_sizes, int n_in,
                              void* d_out, int out_size, void* d_ws, size_t ws_size,
                              hipStream_t stream) {
    const float* xl   = (const float*)d_in[0];
    const float* xh   = (const float*)d_in[1];
    const float* zstd = (const float*)d_in[2];
    const int* si_lh  = (const int*)d_in[3];
    const int* di_lh  = (const int*)d_in[4];
    const int* si_hh  = (const int*)d_in[5];
    const int* di_hh  = (const int*)d_in[6];
    int a = 7;
    const float *d_Wl = (const float*)d_in[a++], *d_bl = (const float*)d_in[a++],
                *d_Wr = (const float*)d_in[a++], *d_br = (const float*)d_in[a++],
                *d_att = (const float*)d_in[a++], *d_b = (const float*)d_in[a++];
    const float *p1_Wl = (const float*)d_in[a++], *p1_bl = (const float*)d_in[a++],
                *p1_Wr = (const float*)d_in[a++], *p1_br = (const float*)d_in[a++],
                *p1_att = (const float*)d_in[a++], *p1_b = (const float*)d_in[a++];
    const float *p2_Wl = (const float*)d_in[a++], *p2_bl = (const float*)d_in[a++],
                *p2_Wr = (const float*)d_in[a++], *p2_br = (const float*)d_in[a++],
                *p2_att = (const float*)d_in[a++], *p2_b = (const float*)d_in[a++];
    const float *p3_Wl = (const float*)d_in[a++], *p3_bl = (const float*)d_in[a++],
                *p3_Wr = (const float*)d_in[a++], *p3_br = (const float*)d_in[a++],
                *p3_att = (const float*)d_in[a++], *p3_b = (const float*)d_in[a++];
    const float *bn0_g = (const float*)d_in[a++], *bn0_b = (const float*)d_in[a++],
                *bn1_g = (const float*)d_in[a++], *bn1_b = (const float*)d_in[a++],
                *bn2_g = (const float*)d_in[a++], *bn2_b = (const float*)d_in[a++],
                *bn3_g = (const float*)d_in[a++], *bn3_b = (const float*)d_in[a++];
    const float *pr_W1 = (const float*)d_in[a++], *pr_b1 = (const float*)d_in[a++],
                *pr_W2 = (const float*)d_in[a++], *pr_b2 = (const float*)d_in[a++];
    float* y = (float*)d_out;

    const int N = N_HIGH;
    const int NMT = 3125;           // 50000/16
    // ---- workspace layout ----
    float* ws = (float*)d_ws;
    float* xA = ws;                           // 50000*257 f32 (also hosts Af)
    float* xB = xA + (size_t)N * 257;         // 50000*256 f32 (also hosts Af)
    float* hl = xB + (size_t)N * 256;         // 50000*256 f32
    float* hr = hl + (size_t)N * 256;         // 50000*256 f32
    bf16x8* xl_f = (bf16x8*)(hr + (size_t)N * 256);   // 320*4*64 frags
    bf16x8* wf_d   = xl_f + 320 * 4 * 64;     // 16*4*64
    bf16x8* wf_p1l = wf_d + 16 * 4 * 64;      // 16*9*64
    bf16x8* wf_p1r = wf_p1l + 16 * 9 * 64;
    bf16x8* wf_p2l = wf_p1r + 16 * 9 * 64;    // 16*8*64
    bf16x8* wf_p2r = wf_p2l + 16 * 8 * 64;
    bf16x8* wf_p3l = wf_p2r + 16 * 8 * 64;    // 4*8*64
    bf16x8* wf_p3r = wf_p3l + 4 * 8 * 64;
    bf16x8* wf_pr1 = wf_p3r + 4 * 8 * 64;     // 4*2*64
    float* bnm = (float*)(wf_pr1 + 4 * 2 * 64);  // 257
    float* bni = bnm + 257;                   // 257
    float* bsum = bni + 257;                  // 514 (sum | sumsq)
    int* itmp   = (int*)(bsum + 514);         // 50000
    int* rp_lh  = itmp + N;                   // 50001
    int* rp_hh  = rp_lh + (N + 1);            // 50001
    int* cur    = rp_hh + (N + 1);            // 50000
    int* csr_lh = cur + N;                    // 200000
    int* csr_hh = csr_lh + E_LH;              // 450000
    int* src2   = csr_hh + E2;                // 450000
    int* dst2   = src2 + E2;                  // 450000
    size_t need = (size_t)((char*)(dst2 + E2) - (char*)ws);
    if (ws_size < need) return;
    bf16x8* AfB = (bf16x8*)xB;   // A-frags overlaying xB (while xB dead)
    bf16x8* AfA = (bf16x8*)xA;   // A-frags overlaying xA (while xA dead)

    dim3 blk(256);
    auto wgrid = [](int E) { return dim3((E + 3) / 4); };
    auto egrid = [](size_t total) {
        size_t g = (total + 255) / 256;
        return dim3((unsigned)(g > 2048 ? 2048 : g));
    };
    auto bn_run = [&](const float* x, int F, float* mean, float* istd) {
        hipMemsetAsync(bsum, 0, 2 * (size_t)F * sizeof(float), stream);
        bn_partial<<<dim3(512), blk, 0, stream>>>(x, N, F, bsum);
        bn_finalize<<<dim3(1), blk, 0, stream>>>(bsum, N, F, mean, istd);
    };

    // ===================== weight fragment transforms =======================
    wt_frag<<<dim3(16), blk, 0, stream>>>(d_Wl, 125, 256, wf_d, 16, 4);
    wt_frag<<<dim3(36), blk, 0, stream>>>(p1_Wl, 257, 256, wf_p1l, 16, 9);
    wt_frag<<<dim3(36), blk, 0, stream>>>(p1_Wr, 257, 256, wf_p1r, 16, 9);
    wt_frag<<<dim3(32), blk, 0, stream>>>(p2_Wl, 256, 256, wf_p2l, 16, 8);
    wt_frag<<<dim3(32), blk, 0, stream>>>(p2_Wr, 256, 256, wf_p2r, 16, 8);
    wt_frag<<<dim3(8),  blk, 0, stream>>>(p3_Wl, 256, 64, wf_p3l, 4, 8);
    wt_frag<<<dim3(8),  blk, 0, stream>>>(p3_Wr, 256, 64, wf_p3r, 4, 8);
    wt_frag<<<dim3(2),  blk, 0, stream>>>(pr_W1, 64, 64, wf_pr1, 4, 2);
    cast_frag<<<dim3(320), blk, 0, stream>>>(xl, N_LOW, 125, xl_f, 320, 4);

    // ===================== CSR builds =======================================
    hipMemsetAsync(itmp, 0, (size_t)N * sizeof(int), stream);
    hist_dst<<<egrid(E_LH), blk, 0, stream>>>(di_lh, itmp, E_LH);
    exscan<<<dim3(1), blk, 0, stream>>>(itmp, rp_lh, N);
    hipMemcpyAsync(cur, rp_lh, (size_t)N * sizeof(int), hipMemcpyDeviceToDevice, stream);
    scatter_csr<<<egrid(E_LH), blk, 0, stream>>>(si_lh, di_lh, cur, csr_lh, E_LH);
    build_edges<<<egrid(E2), blk, 0, stream>>>(si_hh, di_hh, src2, dst2, E_HH, N);
    hipMemsetAsync(itmp, 0, (size_t)N * sizeof(int), stream);
    hist_dst<<<egrid(E2), blk, 0, stream>>>(dst2, itmp, E2);
    exscan<<<dim3(1), blk, 0, stream>>>(itmp, rp_hh, N);
    hipMemcpyAsync(cur, rp_hh, (size_t)N * sizeof(int), hipMemcpyDeviceToDevice, stream);
    scatter_csr<<<egrid(E2), blk, 0, stream>>>(src2, dst2, cur, csr_hh, E2);

    // ===================== d layer (low -> high, H=1, C=256) ================
    gemm_mfma<false><<<dim3(4, 40), blk, 0, stream>>>(xl_f, wf_d, d_bl, hl, N_LOW, 256, 4);
    outer_hr<<<egrid((size_t)N * 64), blk, 0, stream>>>(xh, d_Wr, d_br, hr, N);
    gat_gather<1, 256><<<wgrid(N), blk, 0, stream>>>(hl, hr, rp_lh, csr_lh, d_att, d_b, xA, 257, 1, N);
    copy_col0<<<egrid(N), blk, 0, stream>>>(zstd, xA, N);

    // ===================== bn0 + frag cast ==================================
    bn_run(xA, 257, bnm, bni);
    bn_frag<false><<<dim3(2048), blk, 0, stream>>>(xA, N, 257, bnm, bni, bn0_g, bn0_b, AfB, NMT, 9);

    // ===================== p1 (H=4, C=64) ===================================
    gemm_mfma<false><<<dim3(4, 391), blk, 0, stream>>>(AfB, wf_p1l, p1_bl, hl, N, 256, 9);
    gemm_mfma<false><<<dim3(4, 391), blk, 0, stream>>>(AfB, wf_p1r, p1_br, hr, N, 256, 9);
    gat_gather<4, 64><<<wgrid(N), blk, 0, stream>>>(hl, hr, rp_hh, csr_hh, p1_att, p1_b, xB, 256, 0, N);
    bn_run(xB, 256, bnm, bni);
    bn_frag<true><<<dim3(2048), blk, 0, stream>>>(xB, N, 256, bnm, bni, bn1_g, bn1_b, AfA, NMT, 8);

    // ===================== p2 (H=4, C=64) ===================================
    gemm_mfma<false><<<dim3(4, 391), blk, 0, stream>>>(AfA, wf_p2l, p2_bl, hl, N, 256, 8);
    gemm_mfma<false><<<dim3(4, 391), blk, 0, stream>>>(AfA, wf_p2r, p2_br, hr, N, 256, 8);
    gat_gather<4, 64><<<wgrid(N), blk, 0, stream>>>(hl, hr, rp_hh, csr_hh, p2_att, p2_b, xA, 256, 0, N);
    bn_run(xA, 256, bnm, bni);
    bn_frag<true><<<dim3(2048), blk, 0, stream>>>(xA, N, 256, bnm, bni, bn2_g, bn2_b, AfB, NMT, 8);

    // ===================== p3 (H=1, C=64) ===================================
    gemm_mfma<false><<<dim3(1, 391), blk, 0, stream>>>(AfB, wf_p3l, p3_bl, hl, N, 64, 8);
    gemm_mfma<false><<<dim3(1, 391), blk, 0, stream>>>(AfB, wf_p3r, p3_br, hr, N, 64, 8);
    gat_gather<1, 64><<<wgrid(N), blk, 0, stream>>>(hl, hr, rp_hh, csr_hh, p3_att, p3_b, xB, 64, 0, N);
    bn_run(xB, 64, bnm, bni);
    bn_frag<true><<<dim3(2048), blk, 0, stream>>>(xB, N, 64, bnm, bni, bn3_g, bn3_b, AfA, NMT, 2);

    // ===================== predictor MLP ====================================
    gemm_mfma<true><<<dim3(1, 391), blk, 0, stream>>>(AfA, wf_pr1, pr_b1, hl, N, 64, 2);
    dot_w2<<<wgrid(N), blk, 0, stream>>>(hl, pr_W2, pr_b2, y, N);
}

// Round 5
// 1012.846 us; speedup vs baseline: 2.8334x; 1.0423x over previous
//
#include <hip/hip_runtime.h>
#include <math.h>

#define DEV __device__ __forceinline__

static const int N_LOW = 5000, N_HIGH = 50000, E_LH = 200000, E_HH = 400000;
static const int E2 = E_HH + N_HIGH; // 450000 with self loops

typedef __attribute__((ext_vector_type(8))) short bf16x8;
typedef __attribute__((ext_vector_type(4))) float f32x4;

DEV float lrelu(float v) { return v >= 0.f ? v : 0.2f * v; }
DEV short f2bf(float v) {            // round-to-nearest-even f32 -> bf16
    unsigned u = __float_as_uint(v);
    u += 0x7FFFu + ((u >> 16) & 1u);
    return (short)(u >> 16);
}
DEV float bf2f(unsigned short u) { return __uint_as_float(((unsigned)u) << 16); }

// =================== MFMA GEMM on fragment-ordered operands =================
// Af: [nmt][nkt][64 lanes][8 bf16]  lane l, j -> A[mt*16 + (l&15)][kt*32 + (l>>4)*8 + j]
// Bf: [nnt][nkt][64 lanes][8 bf16]  lane l, j -> B[kt*32 + (l>>4)*8 + j][nt*16 + (l&15)]
// Block: 4 waves; wave w covers rows [bm + w*32, +32) x cols [bn, +64).
// BF16OUT: C is written as packed bf16 (ushort) instead of f32.
template <bool RELU, bool BF16OUT>
__global__ __launch_bounds__(256) void gemm_mfma(
    const bf16x8* __restrict__ Af, const bf16x8* __restrict__ Bf,
    const float* __restrict__ bias, float* __restrict__ C,
    int M, int N, int nkt) {
    const int l = threadIdx.x & 63;
    const int w = threadIdx.x >> 6;
    const int nt0 = blockIdx.x * 4;
    const int mt0 = blockIdx.y * 8 + w * 2;
    f32x4 acc[2][4];
#pragma unroll
    for (int i = 0; i < 2; i++)
#pragma unroll
        for (int j = 0; j < 4; j++) acc[i][j] = (f32x4){0.f, 0.f, 0.f, 0.f};
    const bf16x8* a0p = Af + (size_t)mt0 * nkt * 64 + l;
    const bf16x8* a1p = a0p + (size_t)nkt * 64;
    const bf16x8* bp = Bf + (size_t)nt0 * nkt * 64 + l;
    for (int kt = 0; kt < nkt; kt++) {
        bf16x8 a0 = a0p[kt * 64];
        bf16x8 a1 = a1p[kt * 64];
        bf16x8 b0 = bp[kt * 64];
        bf16x8 b1 = bp[(size_t)(nkt + kt) * 64];
        bf16x8 b2 = bp[(size_t)(2 * nkt + kt) * 64];
        bf16x8 b3 = bp[(size_t)(3 * nkt + kt) * 64];
        acc[0][0] = __builtin_amdgcn_mfma_f32_16x16x32_bf16(a0, b0, acc[0][0], 0, 0, 0);
        acc[0][1] = __builtin_amdgcn_mfma_f32_16x16x32_bf16(a0, b1, acc[0][1], 0, 0, 0);
        acc[0][2] = __builtin_amdgcn_mfma_f32_16x16x32_bf16(a0, b2, acc[0][2], 0, 0, 0);
        acc[0][3] = __builtin_amdgcn_mfma_f32_16x16x32_bf16(a0, b3, acc[0][3], 0, 0, 0);
        acc[1][0] = __builtin_amdgcn_mfma_f32_16x16x32_bf16(a1, b0, acc[1][0], 0, 0, 0);
        acc[1][1] = __builtin_amdgcn_mfma_f32_16x16x32_bf16(a1, b1, acc[1][1], 0, 0, 0);
        acc[1][2] = __builtin_amdgcn_mfma_f32_16x16x32_bf16(a1, b2, acc[1][2], 0, 0, 0);
        acc[1][3] = __builtin_amdgcn_mfma_f32_16x16x32_bf16(a1, b3, acc[1][3], 0, 0, 0);
    }
    const int colb = nt0 * 16 + (l & 15);
    const int rsub = (l >> 4) * 4;
#pragma unroll
    for (int mi = 0; mi < 2; mi++) {
        int rowb = (mt0 + mi) * 16 + rsub;
#pragma unroll
        for (int r = 0; r < 4; r++) {
            int row = rowb + r;
            if (row >= M) continue;
#pragma unroll
            for (int n = 0; n < 4; n++) {
                int col = colb + n * 16;
                float v = acc[mi][n][r] + bias[col];
                if (RELU) v = fmaxf(v, 0.f);
                if (BF16OUT)
                    ((unsigned short*)C)[(size_t)row * N + col] = (unsigned short)f2bf(v);
                else
                    C[(size_t)row * N + col] = v;
            }
        }
    }
}

// --------- BN-apply + (relu) + bf16 cast into fragment-ordered A -----------
template <bool RELU>
__global__ __launch_bounds__(256) void bn_frag(
    const float* __restrict__ x, int Nrows, int F,
    const float* __restrict__ mean, const float* __restrict__ istd,
    const float* __restrict__ g, const float* __restrict__ b,
    bf16x8* __restrict__ Af, int nmt, int nkt) {
    int total = nmt * nkt * 64;
    for (int idx = blockIdx.x * blockDim.x + threadIdx.x; idx < total;
         idx += gridDim.x * blockDim.x) {
        int mt = idx / (nkt * 64);
        int rem = idx - mt * (nkt * 64);
        int kt = rem >> 6, l = rem & 63;
        int row = mt * 16 + (l & 15);
        int colb = kt * 32 + (l >> 4) * 8;
        bf16x8 o;
#pragma unroll
        for (int j = 0; j < 8; j++) {
            int col = colb + j;
            float v = 0.f;
            if (row < Nrows && col < F) {
                v = (x[(size_t)row * F + col] - mean[col]) * istd[col] * g[col] + b[col];
                if (RELU) v = fmaxf(v, 0.f);
            }
            o[j] = f2bf(v);
        }
        Af[idx] = o;
    }
}

// --------- plain cast (xl) into fragment-ordered A, zero-padded -----------
__global__ __launch_bounds__(256) void cast_frag(
    const float* __restrict__ x, int Nrows, int F,
    bf16x8* __restrict__ Af, int nmt, int nkt) {
    int total = nmt * nkt * 64;
    for (int idx = blockIdx.x * blockDim.x + threadIdx.x; idx < total;
         idx += gridDim.x * blockDim.x) {
        int mt = idx / (nkt * 64);
        int rem = idx - mt * (nkt * 64);
        int kt = rem >> 6, l = rem & 63;
        int row = mt * 16 + (l & 15);
        int colb = kt * 32 + (l >> 4) * 8;
        bf16x8 o;
#pragma unroll
        for (int j = 0; j < 8; j++) {
            int col = colb + j;
            o[j] = (row < Nrows && col < F) ? f2bf(x[(size_t)row * F + col]) : (short)0;
        }
        Af[idx] = o;
    }
}

// --------- weight [K][N] -> fragment-ordered B, zero-padded ----------------
__global__ __launch_bounds__(256) void wt_frag(
    const float* __restrict__ W, int K, int N,
    bf16x8* __restrict__ Bf, int nnt, int nkt) {
    int total = nnt * nkt * 64;
    for (int idx = blockIdx.x * blockDim.x + threadIdx.x; idx < total;
         idx += gridDim.x * blockDim.x) {
        int nt = idx / (nkt * 64);
        int rem = idx - nt * (nkt * 64);
        int kt = rem >> 6, l = rem & 63;
        int col = nt * 16 + (l & 15);
        int kb = kt * 32 + (l >> 4) * 8;
        bf16x8 o;
#pragma unroll
        for (int j = 0; j < 8; j++) {
            int k = kb + j;
            o[j] = (k < K && col < N) ? f2bf(W[(size_t)k * N + col]) : (short)0;
        }
        Bf[idx] = o;
    }
}

// --------- hr = xh * Wr + br  (K=1 outer product), bf16 output -------------
__global__ __launch_bounds__(256) void outer_hr(
    const float* __restrict__ xh, const float* __restrict__ Wr,
    const float* __restrict__ br, unsigned short* __restrict__ hr, int N) {
    int total = N * 64;
    for (int i = blockIdx.x * blockDim.x + threadIdx.x; i < total;
         i += gridDim.x * blockDim.x) {
        int n = i >> 6, c = (i & 63) * 4;
        float x = xh[n];
        float4 w = *reinterpret_cast<const float4*>(Wr + c);
        float4 b = *reinterpret_cast<const float4*>(br + c);
        ushort4 o;
        o.x = (unsigned short)f2bf(fmaf(x, w.x, b.x));
        o.y = (unsigned short)f2bf(fmaf(x, w.y, b.y));
        o.z = (unsigned short)f2bf(fmaf(x, w.z, b.z));
        o.w = (unsigned short)f2bf(fmaf(x, w.w, b.w));
        *reinterpret_cast<ushort4*>(hr + (size_t)n * 256 + c) = o;
    }
}

// ------------------- CSR build: histogram / scan / scatter -----------------
__global__ __launch_bounds__(256) void hist_dst(const int* __restrict__ dst,
                                                int* __restrict__ cnt, int E) {
    for (int i = blockIdx.x * blockDim.x + threadIdx.x; i < E;
         i += gridDim.x * blockDim.x)
        atomicAdd(&cnt[dst[i]], 1);
}

__global__ __launch_bounds__(256) void exscan(const int* __restrict__ cnt,
                                              int* __restrict__ off, int N) {
    __shared__ int s[256];
    const int tid = threadIdx.x;
    const int chunk = (N + 255) / 256;
    int lo = tid * chunk, hi = lo + chunk;
    if (hi > N) hi = N;
    int sum = 0;
    for (int i = lo; i < hi; i++) sum += cnt[i];
    s[tid] = sum;
    __syncthreads();
    for (int step = 1; step < 256; step <<= 1) {
        int v = (tid >= step) ? s[tid - step] : 0;
        __syncthreads();
        s[tid] += v;
        __syncthreads();
    }
    int run = (tid > 0) ? s[tid - 1] : 0;
    for (int i = lo; i < hi; i++) {
        off[i] = run;
        run += cnt[i];
    }
    if (tid == 255) off[N] = run;
}

__global__ __launch_bounds__(256) void scatter_csr(const int* __restrict__ src,
                                                   const int* __restrict__ dst,
                                                   int* __restrict__ cur,
                                                   int* __restrict__ csr, int E) {
    for (int i = blockIdx.x * blockDim.x + threadIdx.x; i < E;
         i += gridDim.x * blockDim.x) {
        int p = atomicAdd(&cur[dst[i]], 1);
        csr[p] = src[i];
    }
}

__global__ __launch_bounds__(256) void build_edges(
    const int* __restrict__ si, const int* __restrict__ di,
    int* __restrict__ src2, int* __restrict__ dst2, int Ehh, int N) {
    int total = Ehh + N;
    for (int i = blockIdx.x * blockDim.x + threadIdx.x; i < total;
         i += gridDim.x * blockDim.x) {
        if (i < Ehh) { src2[i] = si[i]; dst2[i] = di[i]; }
        else { src2[i] = i - Ehh; dst2[i] = i - Ehh; }
    }
}

// ---------- fused GATv2 (bf16 hl/hr): logit + online softmax + mean + bias -
template <int H, int C>
__global__ __launch_bounds__(256) void gat_gather(
    const unsigned short* __restrict__ hl, const unsigned short* __restrict__ hr,
    const int* __restrict__ rowptr, const int* __restrict__ csr_src,
    const float* __restrict__ att, const float* __restrict__ bias,
    float* __restrict__ out, int outStride, int outOfs, int Ndst) {
    constexpr int HC = H * C;
    constexpr int VPL = HC / 64;
    constexpr int LPH = C / VPL;
    int w = blockIdx.x * (blockDim.x >> 6) + (threadIdx.x >> 6);
    if (w >= Ndst) return;
    const int l = threadIdx.x & 63;

    float hrv[VPL], attv[VPL];
    if constexpr (VPL == 4) {
        ushort4 t = *(reinterpret_cast<const ushort4*>(hr + (size_t)w * HC) + l);
        hrv[0] = bf2f(t.x); hrv[1] = bf2f(t.y); hrv[2] = bf2f(t.z); hrv[3] = bf2f(t.w);
        float4 u = *reinterpret_cast<const float4*>(att + l * 4);
        attv[0] = u.x; attv[1] = u.y; attv[2] = u.z; attv[3] = u.w;
    } else {
#pragma unroll
        for (int j = 0; j < VPL; j++) {
            hrv[j] = bf2f(hr[(size_t)w * HC + l * VPL + j]);
            attv[j] = att[l * VPL + j];
        }
    }

    const int e0 = rowptr[w], e1 = rowptr[w + 1];
    float m = -3.4e38f, s = 0.f;
    float acc[VPL] = {};
    for (int e = e0; e < e1; e++) {
        int sv = csr_src[e];
        float hlv[VPL];
        if constexpr (VPL == 4) {
            ushort4 t = *(reinterpret_cast<const ushort4*>(hl + (size_t)sv * HC) + l);
            hlv[0] = bf2f(t.x); hlv[1] = bf2f(t.y); hlv[2] = bf2f(t.z); hlv[3] = bf2f(t.w);
        } else {
#pragma unroll
            for (int j = 0; j < VPL; j++) hlv[j] = bf2f(hl[(size_t)sv * HC + l * VPL + j]);
        }
        float v = 0.f;
#pragma unroll
        for (int j = 0; j < VPL; j++) v += lrelu(hlv[j] + hrv[j]) * attv[j];
#pragma unroll
        for (int t = 1; t < LPH; t <<= 1) v += __shfl_xor(v, t, 64);
        // single-exp online softmax update
        float d = v - m;
        bool up = d > 0.f;
        float e1f = __expf(-fabsf(d));   // first edge: d=inf -> e1f=0
        float sc = up ? e1f : 1.f;
        float p  = up ? 1.f : e1f;
        m = up ? v : m;
        s = fmaf(s, sc, p);
#pragma unroll
        for (int j = 0; j < VPL; j++) acc[j] = fmaf(acc[j], sc, p * hlv[j]);
    }
    float inv = 1.f / (s + 1e-16f);
    float dnorm = inv / fmaxf((float)(e1 - e0), 1.f);
#pragma unroll
    for (int j = 0; j < VPL; j++)
        out[(size_t)w * outStride + outOfs + l * VPL + j] =
            acc[j] * dnorm + bias[l * VPL + j];
}

__global__ __launch_bounds__(256) void copy_col0(const float* __restrict__ zstd,
                                                 float* __restrict__ xA, int N) {
    for (int i = blockIdx.x * blockDim.x + threadIdx.x; i < N;
         i += gridDim.x * blockDim.x)
        xA[(size_t)i * 257] = zstd[i];
}

// ----------- BN stats, row-parallel: coalesced partial sums + atomics ------
// sums[0..F) = sum, sums[F..2F) = sumsq. Must be zeroed before launch.
__global__ __launch_bounds__(256) void bn_partial(
    const float* __restrict__ x, int Nrows, int F, float* __restrict__ sums) {
    const int t = threadIdx.x;
    if (F == 64) {
        int col = t & 63, rofs = t >> 6;
        float s1 = 0.f, s2 = 0.f;
        for (int r0 = blockIdx.x * 8; r0 < Nrows; r0 += gridDim.x * 8) {
#pragma unroll
            for (int u = 0; u < 2; u++) {
                int r = r0 + u * 4 + rofs;
                if (r < Nrows) {
                    float v = x[(size_t)r * 64 + col];
                    s1 += v; s2 += v * v;
                }
            }
        }
        atomicAdd(&sums[col], s1);
        atomicAdd(&sums[64 + col], s2);
    } else {
        const bool extra = (F > 256) && (t < F - 256);
        float a1 = 0.f, a2 = 0.f, b1 = 0.f, b2 = 0.f;
        for (int r0 = blockIdx.x * 2; r0 < Nrows; r0 += gridDim.x * 2) {
#pragma unroll
            for (int u = 0; u < 2; u++) {
                int r = r0 + u;
                if (r < Nrows) {
                    const float* row = x + (size_t)r * F;
                    float v = row[t];
                    a1 += v; a2 += v * v;
                    if (extra) {
                        float q = row[t + 256];
                        b1 += q; b2 += q * q;
                    }
                }
            }
        }
        atomicAdd(&sums[t], a1);
        atomicAdd(&sums[F + t], a2);
        if (extra) {
            atomicAdd(&sums[t + 256], b1);
            atomicAdd(&sums[F + t + 256], b2);
        }
    }
}

__global__ __launch_bounds__(256) void bn_finalize(
    const float* __restrict__ sums, int Nrows, int F,
    float* __restrict__ mean, float* __restrict__ istd) {
    for (int t = threadIdx.x; t < F; t += 256) {
        float mu = sums[t] / Nrows;
        float var = sums[F + t] / Nrows - mu * mu;
        mean[t] = mu;
        istd[t] = rsqrtf(fmaxf(var, 0.f) + 1e-5f);
    }
}

// y[i] = dot64(hid[i], W2) + b2
__global__ __launch_bounds__(256) void dot_w2(const float* __restrict__ hid,
                                              const float* __restrict__ W2,
                                              const float* __restrict__ b2,
                                              float* __restrict__ y, int N) {
    int w = blockIdx.x * (blockDim.x >> 6) + (threadIdx.x >> 6);
    int l = threadIdx.x & 63;
    if (w >= N) return;
    float v = hid[(size_t)w * 64 + l] * W2[l];
#pragma unroll
    for (int m = 1; m < 64; m <<= 1) v += __shfl_xor(v, m, 64);
    if (l == 0) y[w] = v + b2[0];
}

// ---------------------------------------------------------------------------
extern "C" void kernel_launch(void* const* d_in, const int* in_sizes, int n_in,
                              void* d_out, int out_size, void* d_ws, size_t ws_size,
                              hipStream_t stream) {
    const float* xl   = (const float*)d_in[0];
    const float* xh   = (const float*)d_in[1];
    const float* zstd = (const float*)d_in[2];
    const int* si_lh  = (const int*)d_in[3];
    const int* di_lh  = (const int*)d_in[4];
    const int* si_hh  = (const int*)d_in[5];
    const int* di_hh  = (const int*)d_in[6];
    int a = 7;
    const float *d_Wl = (const float*)d_in[a++], *d_bl = (const float*)d_in[a++],
                *d_Wr = (const float*)d_in[a++], *d_br = (const float*)d_in[a++],
                *d_att = (const float*)d_in[a++], *d_b = (const float*)d_in[a++];
    const float *p1_Wl = (const float*)d_in[a++], *p1_bl = (const float*)d_in[a++],
                *p1_Wr = (const float*)d_in[a++], *p1_br = (const float*)d_in[a++],
                *p1_att = (const float*)d_in[a++], *p1_b = (const float*)d_in[a++];
    const float *p2_Wl = (const float*)d_in[a++], *p2_bl = (const float*)d_in[a++],
                *p2_Wr = (const float*)d_in[a++], *p2_br = (const float*)d_in[a++],
                *p2_att = (const float*)d_in[a++], *p2_b = (const float*)d_in[a++];
    const float *p3_Wl = (const float*)d_in[a++], *p3_bl = (const float*)d_in[a++],
                *p3_Wr = (const float*)d_in[a++], *p3_br = (const float*)d_in[a++],
                *p3_att = (const float*)d_in[a++], *p3_b = (const float*)d_in[a++];
    const float *bn0_g = (const float*)d_in[a++], *bn0_b = (const float*)d_in[a++],
                *bn1_g = (const float*)d_in[a++], *bn1_b = (const float*)d_in[a++],
                *bn2_g = (const float*)d_in[a++], *bn2_b = (const float*)d_in[a++],
                *bn3_g = (const float*)d_in[a++], *bn3_b = (const float*)d_in[a++];
    const float *pr_W1 = (const float*)d_in[a++], *pr_b1 = (const float*)d_in[a++],
                *pr_W2 = (const float*)d_in[a++], *pr_b2 = (const float*)d_in[a++];
    float* y = (float*)d_out;

    const int N = N_HIGH;
    const int NMT = 3125;           // 50000/16
    // ---- workspace layout ----
    float* ws = (float*)d_ws;
    float* xA = ws;                           // 50000*257 f32 (also hosts Af)
    float* xB = xA + (size_t)N * 257;         // 50000*256 f32 (also hosts Af)
    float* hl = xB + (size_t)N * 256;         // 50000*256 f32 (bf16 actually used)
    float* hr = hl + (size_t)N * 256;         // 50000*256 f32 (bf16 actually used)
    bf16x8* xl_f = (bf16x8*)(hr + (size_t)N * 256);   // 320*4*64 frags
    bf16x8* wf_d   = xl_f + 320 * 4 * 64;     // 16*4*64
    bf16x8* wf_p1l = wf_d + 16 * 4 * 64;      // 16*9*64
    bf16x8* wf_p1r = wf_p1l + 16 * 9 * 64;
    bf16x8* wf_p2l = wf_p1r + 16 * 9 * 64;    // 16*8*64
    bf16x8* wf_p2r = wf_p2l + 16 * 8 * 64;
    bf16x8* wf_p3l = wf_p2r + 16 * 8 * 64;    // 4*8*64
    bf16x8* wf_p3r = wf_p3l + 4 * 8 * 64;
    bf16x8* wf_pr1 = wf_p3r + 4 * 8 * 64;     // 4*2*64
    float* bnm = (float*)(wf_pr1 + 4 * 2 * 64);  // 257
    float* bni = bnm + 257;                   // 257
    float* bsum = bni + 257;                  // 514 (sum | sumsq)
    int* itmp   = (int*)(bsum + 514);         // 50000
    int* rp_lh  = itmp + N;                   // 50001
    int* rp_hh  = rp_lh + (N + 1);            // 50001
    int* cur    = rp_hh + (N + 1);            // 50000
    int* csr_lh = cur + N;                    // 200000
    int* csr_hh = csr_lh + E_LH;              // 450000
    int* src2   = csr_hh + E2;                // 450000
    int* dst2   = src2 + E2;                  // 450000
    size_t need = (size_t)((char*)(dst2 + E2) - (char*)ws);
    if (ws_size < need) return;
    bf16x8* AfB = (bf16x8*)xB;   // A-frags overlaying xB (while xB dead)
    bf16x8* AfA = (bf16x8*)xA;   // A-frags overlaying xA (while xA dead)
    unsigned short* hl16 = (unsigned short*)hl;
    unsigned short* hr16 = (unsigned short*)hr;

    dim3 blk(256);
    auto wgrid = [](int E) { return dim3((E + 3) / 4); };
    auto egrid = [](size_t total) {
        size_t g = (total + 255) / 256;
        return dim3((unsigned)(g > 2048 ? 2048 : g));
    };
    auto bn_run = [&](const float* x, int F, float* mean, float* istd) {
        hipMemsetAsync(bsum, 0, 2 * (size_t)F * sizeof(float), stream);
        bn_partial<<<dim3(512), blk, 0, stream>>>(x, N, F, bsum);
        bn_finalize<<<dim3(1), blk, 0, stream>>>(bsum, N, F, mean, istd);
    };

    // ===================== weight fragment transforms =======================
    wt_frag<<<dim3(16), blk, 0, stream>>>(d_Wl, 125, 256, wf_d, 16, 4);
    wt_frag<<<dim3(36), blk, 0, stream>>>(p1_Wl, 257, 256, wf_p1l, 16, 9);
    wt_frag<<<dim3(36), blk, 0, stream>>>(p1_Wr, 257, 256, wf_p1r, 16, 9);
    wt_frag<<<dim3(32), blk, 0, stream>>>(p2_Wl, 256, 256, wf_p2l, 16, 8);
    wt_frag<<<dim3(32), blk, 0, stream>>>(p2_Wr, 256, 256, wf_p2r, 16, 8);
    wt_frag<<<dim3(8),  blk, 0, stream>>>(p3_Wl, 256, 64, wf_p3l, 4, 8);
    wt_frag<<<dim3(8),  blk, 0, stream>>>(p3_Wr, 256, 64, wf_p3r, 4, 8);
    wt_frag<<<dim3(2),  blk, 0, stream>>>(pr_W1, 64, 64, wf_pr1, 4, 2);
    cast_frag<<<dim3(320), blk, 0, stream>>>(xl, N_LOW, 125, xl_f, 320, 4);

    // ===================== CSR builds =======================================
    hipMemsetAsync(itmp, 0, (size_t)N * sizeof(int), stream);
    hist_dst<<<egrid(E_LH), blk, 0, stream>>>(di_lh, itmp, E_LH);
    exscan<<<dim3(1), blk, 0, stream>>>(itmp, rp_lh, N);
    hipMemcpyAsync(cur, rp_lh, (size_t)N * sizeof(int), hipMemcpyDeviceToDevice, stream);
    scatter_csr<<<egrid(E_LH), blk, 0, stream>>>(si_lh, di_lh, cur, csr_lh, E_LH);
    build_edges<<<egrid(E2), blk, 0, stream>>>(si_hh, di_hh, src2, dst2, E_HH, N);
    hipMemsetAsync(itmp, 0, (size_t)N * sizeof(int), stream);
    hist_dst<<<egrid(E2), blk, 0, stream>>>(dst2, itmp, E2);
    exscan<<<dim3(1), blk, 0, stream>>>(itmp, rp_hh, N);
    hipMemcpyAsync(cur, rp_hh, (size_t)N * sizeof(int), hipMemcpyDeviceToDevice, stream);
    scatter_csr<<<egrid(E2), blk, 0, stream>>>(src2, dst2, cur, csr_hh, E2);

    // ===================== d layer (low -> high, H=1, C=256) ================
    gemm_mfma<false, true><<<dim3(4, 40), blk, 0, stream>>>(xl_f, wf_d, d_bl, hl, N_LOW, 256, 4);
    outer_hr<<<egrid((size_t)N * 64), blk, 0, stream>>>(xh, d_Wr, d_br, hr16, N);
    gat_gather<1, 256><<<wgrid(N), blk, 0, stream>>>(hl16, hr16, rp_lh, csr_lh, d_att, d_b, xA, 257, 1, N);
    copy_col0<<<egrid(N), blk, 0, stream>>>(zstd, xA, N);

    // ===================== bn0 + frag cast ==================================
    bn_run(xA, 257, bnm, bni);
    bn_frag<false><<<dim3(2048), blk, 0, stream>>>(xA, N, 257, bnm, bni, bn0_g, bn0_b, AfB, NMT, 9);

    // ===================== p1 (H=4, C=64) ===================================
    gemm_mfma<false, true><<<dim3(4, 391), blk, 0, stream>>>(AfB, wf_p1l, p1_bl, hl, N, 256, 9);
    gemm_mfma<false, true><<<dim3(4, 391), blk, 0, stream>>>(AfB, wf_p1r, p1_br, hr, N, 256, 9);
    gat_gather<4, 64><<<wgrid(N), blk, 0, stream>>>(hl16, hr16, rp_hh, csr_hh, p1_att, p1_b, xB, 256, 0, N);
    bn_run(xB, 256, bnm, bni);
    bn_frag<true><<<dim3(2048), blk, 0, stream>>>(xB, N, 256, bnm, bni, bn1_g, bn1_b, AfA, NMT, 8);

    // ===================== p2 (H=4, C=64) ===================================
    gemm_mfma<false, true><<<dim3(4, 391), blk, 0, stream>>>(AfA, wf_p2l, p2_bl, hl, N, 256, 8);
    gemm_mfma<false, true><<<dim3(4, 391), blk, 0, stream>>>(AfA, wf_p2r, p2_br, hr, N, 256, 8);
    gat_gather<4, 64><<<wgrid(N), blk, 0, stream>>>(hl16, hr16, rp_hh, csr_hh, p2_att, p2_b, xA, 256, 0, N);
    bn_run(xA, 256, bnm, bni);
    bn_frag<true><<<dim3(2048), blk, 0, stream>>>(xA, N, 256, bnm, bni, bn2_g, bn2_b, AfB, NMT, 8);

    // ===================== p3 (H=1, C=64) ===================================
    gemm_mfma<false, true><<<dim3(1, 391), blk, 0, stream>>>(AfB, wf_p3l, p3_bl, hl, N, 64, 8);
    gemm_mfma<false, true><<<dim3(1, 391), blk, 0, stream>>>(AfB, wf_p3r, p3_br, hr, N, 64, 8);
    gat_gather<1, 64><<<wgrid(N), blk, 0, stream>>>(hl16, hr16, rp_hh, csr_hh, p3_att, p3_b, xB, 64, 0, N);
    bn_run(xB, 64, bnm, bni);
    bn_frag<true><<<dim3(2048), blk, 0, stream>>>(xB, N, 64, bnm, bni, bn3_g, bn3_b, AfA, NMT, 2);

    // ===================== predictor MLP ====================================
    gemm_mfma<true, false><<<dim3(1, 391), blk, 0, stream>>>(AfA, wf_pr1, pr_b1, hl, N, 64, 2);
    dot_w2<<<wgrid(N), blk, 0, stream>>>(hl, pr_W2, pr_b2, y, N);
}

// Round 6
// 862.449 us; speedup vs baseline: 3.3276x; 1.1744x over previous
//
#include <hip/hip_runtime.h>
#include <math.h>

#define DEV __device__ __forceinline__

static const int N_LOW = 5000, N_HIGH = 50000, E_LH = 200000, E_HH = 400000;
static const int E2 = E_HH + N_HIGH; // 450000 with self loops

typedef __attribute__((ext_vector_type(8))) short bf16x8;
typedef __attribute__((ext_vector_type(4))) float f32x4;

DEV float lrelu(float v) { return v >= 0.f ? v : 0.2f * v; }
DEV short f2bf(float v) {            // round-to-nearest-even f32 -> bf16
    unsigned u = __float_as_uint(v);
    u += 0x7FFFu + ((u >> 16) & 1u);
    return (short)(u >> 16);
}
DEV float bf2f(unsigned short u) { return __uint_as_float(((unsigned)u) << 16); }

// =================== MFMA GEMM on fragment-ordered operands =================
// Af: [nmt][nkt][64 lanes][8 bf16]  lane l, j -> A[mt*16 + (l&15)][kt*32 + (l>>4)*8 + j]
// Bf: [nnt][nkt][64 lanes][8 bf16]  lane l, j -> B[kt*32 + (l>>4)*8 + j][nt*16 + (l&15)]
// Block: 4 waves; wave w covers rows [bm + w*32, +32) x cols [bn, +64).
// BF16OUT: C is written as packed bf16 (ushort) instead of f32.
template <bool RELU, bool BF16OUT>
__global__ __launch_bounds__(256) void gemm_mfma(
    const bf16x8* __restrict__ Af, const bf16x8* __restrict__ Bf,
    const float* __restrict__ bias, float* __restrict__ C,
    int M, int N, int nkt) {
    const int l = threadIdx.x & 63;
    const int w = threadIdx.x >> 6;
    const int nt0 = blockIdx.x * 4;
    const int mt0 = blockIdx.y * 8 + w * 2;
    f32x4 acc[2][4];
#pragma unroll
    for (int i = 0; i < 2; i++)
#pragma unroll
        for (int j = 0; j < 4; j++) acc[i][j] = (f32x4){0.f, 0.f, 0.f, 0.f};
    const bf16x8* a0p = Af + (size_t)mt0 * nkt * 64 + l;
    const bf16x8* a1p = a0p + (size_t)nkt * 64;
    const bf16x8* bp = Bf + (size_t)nt0 * nkt * 64 + l;
    for (int kt = 0; kt < nkt; kt++) {
        bf16x8 a0 = a0p[kt * 64];
        bf16x8 a1 = a1p[kt * 64];
        bf16x8 b0 = bp[kt * 64];
        bf16x8 b1 = bp[(size_t)(nkt + kt) * 64];
        bf16x8 b2 = bp[(size_t)(2 * nkt + kt) * 64];
        bf16x8 b3 = bp[(size_t)(3 * nkt + kt) * 64];
        acc[0][0] = __builtin_amdgcn_mfma_f32_16x16x32_bf16(a0, b0, acc[0][0], 0, 0, 0);
        acc[0][1] = __builtin_amdgcn_mfma_f32_16x16x32_bf16(a0, b1, acc[0][1], 0, 0, 0);
        acc[0][2] = __builtin_amdgcn_mfma_f32_16x16x32_bf16(a0, b2, acc[0][2], 0, 0, 0);
        acc[0][3] = __builtin_amdgcn_mfma_f32_16x16x32_bf16(a0, b3, acc[0][3], 0, 0, 0);
        acc[1][0] = __builtin_amdgcn_mfma_f32_16x16x32_bf16(a1, b0, acc[1][0], 0, 0, 0);
        acc[1][1] = __builtin_amdgcn_mfma_f32_16x16x32_bf16(a1, b1, acc[1][1], 0, 0, 0);
        acc[1][2] = __builtin_amdgcn_mfma_f32_16x16x32_bf16(a1, b2, acc[1][2], 0, 0, 0);
        acc[1][3] = __builtin_amdgcn_mfma_f32_16x16x32_bf16(a1, b3, acc[1][3], 0, 0, 0);
    }
    const int colb = nt0 * 16 + (l & 15);
    const int rsub = (l >> 4) * 4;
#pragma unroll
    for (int mi = 0; mi < 2; mi++) {
        int rowb = (mt0 + mi) * 16 + rsub;
#pragma unroll
        for (int r = 0; r < 4; r++) {
            int row = rowb + r;
            if (row >= M) continue;
#pragma unroll
            for (int n = 0; n < 4; n++) {
                int col = colb + n * 16;
                float v = acc[mi][n][r] + bias[col];
                if (RELU) v = fmaxf(v, 0.f);
                if (BF16OUT)
                    ((unsigned short*)C)[(size_t)row * N + col] = (unsigned short)f2bf(v);
                else
                    C[(size_t)row * N + col] = v;
            }
        }
    }
}

// --------- BN-apply + (relu) + bf16 cast into fragment-ordered A -----------
template <bool RELU>
__global__ __launch_bounds__(256) void bn_frag(
    const float* __restrict__ x, int Nrows, int F,
    const float* __restrict__ mean, const float* __restrict__ istd,
    const float* __restrict__ g, const float* __restrict__ b,
    bf16x8* __restrict__ Af, int nmt, int nkt) {
    int total = nmt * nkt * 64;
    for (int idx = blockIdx.x * blockDim.x + threadIdx.x; idx < total;
         idx += gridDim.x * blockDim.x) {
        int mt = idx / (nkt * 64);
        int rem = idx - mt * (nkt * 64);
        int kt = rem >> 6, l = rem & 63;
        int row = mt * 16 + (l & 15);
        int colb = kt * 32 + (l >> 4) * 8;
        bf16x8 o;
#pragma unroll
        for (int j = 0; j < 8; j++) {
            int col = colb + j;
            float v = 0.f;
            if (row < Nrows && col < F) {
                v = (x[(size_t)row * F + col] - mean[col]) * istd[col] * g[col] + b[col];
                if (RELU) v = fmaxf(v, 0.f);
            }
            o[j] = f2bf(v);
        }
        Af[idx] = o;
    }
}

// --------- plain cast (xl) into fragment-ordered A, zero-padded -----------
__global__ __launch_bounds__(256) void cast_frag(
    const float* __restrict__ x, int Nrows, int F,
    bf16x8* __restrict__ Af, int nmt, int nkt) {
    int total = nmt * nkt * 64;
    for (int idx = blockIdx.x * blockDim.x + threadIdx.x; idx < total;
         idx += gridDim.x * blockDim.x) {
        int mt = idx / (nkt * 64);
        int rem = idx - mt * (nkt * 64);
        int kt = rem >> 6, l = rem & 63;
        int row = mt * 16 + (l & 15);
        int colb = kt * 32 + (l >> 4) * 8;
        bf16x8 o;
#pragma unroll
        for (int j = 0; j < 8; j++) {
            int col = colb + j;
            o[j] = (row < Nrows && col < F) ? f2bf(x[(size_t)row * F + col]) : (short)0;
        }
        Af[idx] = o;
    }
}

// --------- weight [K][N] -> fragment-ordered B, zero-padded ----------------
__global__ __launch_bounds__(256) void wt_frag(
    const float* __restrict__ W, int K, int N,
    bf16x8* __restrict__ Bf, int nnt, int nkt) {
    int total = nnt * nkt * 64;
    for (int idx = blockIdx.x * blockDim.x + threadIdx.x; idx < total;
         idx += gridDim.x * blockDim.x) {
        int nt = idx / (nkt * 64);
        int rem = idx - nt * (nkt * 64);
        int kt = rem >> 6, l = rem & 63;
        int col = nt * 16 + (l & 15);
        int kb = kt * 32 + (l >> 4) * 8;
        bf16x8 o;
#pragma unroll
        for (int j = 0; j < 8; j++) {
            int k = kb + j;
            o[j] = (k < K && col < N) ? f2bf(W[(size_t)k * N + col]) : (short)0;
        }
        Bf[idx] = o;
    }
}

// --------- hr = xh * Wr + br  (K=1 outer product), bf16 output -------------
__global__ __launch_bounds__(256) void outer_hr(
    const float* __restrict__ xh, const float* __restrict__ Wr,
    const float* __restrict__ br, unsigned short* __restrict__ hr, int N) {
    int total = N * 64;
    for (int i = blockIdx.x * blockDim.x + threadIdx.x; i < total;
         i += gridDim.x * blockDim.x) {
        int n = i >> 6, c = (i & 63) * 4;
        float x = xh[n];
        float4 w = *reinterpret_cast<const float4*>(Wr + c);
        float4 b = *reinterpret_cast<const float4*>(br + c);
        ushort4 o;
        o.x = (unsigned short)f2bf(fmaf(x, w.x, b.x));
        o.y = (unsigned short)f2bf(fmaf(x, w.y, b.y));
        o.z = (unsigned short)f2bf(fmaf(x, w.z, b.z));
        o.w = (unsigned short)f2bf(fmaf(x, w.w, b.w));
        *reinterpret_cast<ushort4*>(hr + (size_t)n * 256 + c) = o;
    }
}

// ------------------- CSR build: histogram / scan / scatter -----------------
__global__ __launch_bounds__(256) void hist_dst(const int* __restrict__ dst,
                                                int* __restrict__ cnt, int E) {
    for (int i = blockIdx.x * blockDim.x + threadIdx.x; i < E;
         i += gridDim.x * blockDim.x)
        atomicAdd(&cnt[dst[i]], 1);
}

// ---- parallel exclusive scan over N ints (3 kernels, chunks of 1024) -------
// pass 1: per-block (1024 elems) local exclusive scan + block sums
__global__ __launch_bounds__(256) void scan_partial(
    const int* __restrict__ cnt, int* __restrict__ off,
    int* __restrict__ bsum, int N) {
    __shared__ int s[256];
    const int t = threadIdx.x;
    const int base = blockIdx.x * 1024 + t * 4;
    int v0 = (base < N) ? cnt[base] : 0;
    int v1 = (base + 1 < N) ? cnt[base + 1] : 0;
    int v2 = (base + 2 < N) ? cnt[base + 2] : 0;
    int v3 = (base + 3 < N) ? cnt[base + 3] : 0;
    int tsum = v0 + v1 + v2 + v3;
    s[t] = tsum;
    __syncthreads();
    for (int step = 1; step < 256; step <<= 1) {
        int q = (t >= step) ? s[t - step] : 0;
        __syncthreads();
        s[t] += q;
        __syncthreads();
    }
    int excl = s[t] - tsum;
    if (base < N) off[base] = excl;
    if (base + 1 < N) off[base + 1] = excl + v0;
    if (base + 2 < N) off[base + 2] = excl + v0 + v1;
    if (base + 3 < N) off[base + 3] = excl + v0 + v1 + v2;
    if (t == 255) bsum[blockIdx.x] = s[255];
}

// pass 2: exclusive-scan the (<=256) block sums in place; write off[N]=total
__global__ __launch_bounds__(256) void scan_bsums(
    int* __restrict__ bsum, int nb, int* __restrict__ off, int N) {
    __shared__ int s[256];
    const int t = threadIdx.x;
    int v = (t < nb) ? bsum[t] : 0;
    s[t] = v;
    __syncthreads();
    for (int step = 1; step < 256; step <<= 1) {
        int q = (t >= step) ? s[t - step] : 0;
        __syncthreads();
        s[t] += q;
        __syncthreads();
    }
    if (t < nb) bsum[t] = s[t] - v;          // exclusive
    if (t == 255) off[N] = s[255];           // grand total
}

// pass 3: add scanned block offsets
__global__ __launch_bounds__(256) void scan_add(
    int* __restrict__ off, const int* __restrict__ bsum, int N) {
    int b = blockIdx.x;
    int add = bsum[b];
    int base = b * 1024;
    int end = base + 1024 < N ? base + 1024 : N;
    for (int i = base + threadIdx.x; i < end; i += 256) off[i] += add;
}

__global__ __launch_bounds__(256) void scatter_csr(const int* __restrict__ src,
                                                   const int* __restrict__ dst,
                                                   int* __restrict__ cur,
                                                   int* __restrict__ csr, int E) {
    for (int i = blockIdx.x * blockDim.x + threadIdx.x; i < E;
         i += gridDim.x * blockDim.x) {
        int p = atomicAdd(&cur[dst[i]], 1);
        csr[p] = src[i];
    }
}

__global__ __launch_bounds__(256) void build_edges(
    const int* __restrict__ si, const int* __restrict__ di,
    int* __restrict__ src2, int* __restrict__ dst2, int Ehh, int N) {
    int total = Ehh + N;
    for (int i = blockIdx.x * blockDim.x + threadIdx.x; i < total;
         i += gridDim.x * blockDim.x) {
        if (i < Ehh) { src2[i] = si[i]; dst2[i] = di[i]; }
        else { src2[i] = i - Ehh; dst2[i] = i - Ehh; }
    }
}

// ---------- fused GATv2 (bf16 hl/hr): logit + online softmax + mean + bias -
template <int H, int C>
__global__ __launch_bounds__(256) void gat_gather(
    const unsigned short* __restrict__ hl, const unsigned short* __restrict__ hr,
    const int* __restrict__ rowptr, const int* __restrict__ csr_src,
    const float* __restrict__ att, const float* __restrict__ bias,
    float* __restrict__ out, int outStride, int outOfs, int Ndst) {
    constexpr int HC = H * C;
    constexpr int VPL = HC / 64;
    constexpr int LPH = C / VPL;
    int w = blockIdx.x * (blockDim.x >> 6) + (threadIdx.x >> 6);
    if (w >= Ndst) return;
    const int l = threadIdx.x & 63;

    float hrv[VPL], attv[VPL];
    if constexpr (VPL == 4) {
        ushort4 t = *(reinterpret_cast<const ushort4*>(hr + (size_t)w * HC) + l);
        hrv[0] = bf2f(t.x); hrv[1] = bf2f(t.y); hrv[2] = bf2f(t.z); hrv[3] = bf2f(t.w);
        float4 u = *reinterpret_cast<const float4*>(att + l * 4);
        attv[0] = u.x; attv[1] = u.y; attv[2] = u.z; attv[3] = u.w;
    } else {
#pragma unroll
        for (int j = 0; j < VPL; j++) {
            hrv[j] = bf2f(hr[(size_t)w * HC + l * VPL + j]);
            attv[j] = att[l * VPL + j];
        }
    }

    const int e0 = rowptr[w], e1 = rowptr[w + 1];
    float m = -3.4e38f, s = 0.f;
    float acc[VPL] = {};
    for (int e = e0; e < e1; e++) {
        int sv = csr_src[e];
        float hlv[VPL];
        if constexpr (VPL == 4) {
            ushort4 t = *(reinterpret_cast<const ushort4*>(hl + (size_t)sv * HC) + l);
            hlv[0] = bf2f(t.x); hlv[1] = bf2f(t.y); hlv[2] = bf2f(t.z); hlv[3] = bf2f(t.w);
        } else {
#pragma unroll
            for (int j = 0; j < VPL; j++) hlv[j] = bf2f(hl[(size_t)sv * HC + l * VPL + j]);
        }
        float v = 0.f;
#pragma unroll
        for (int j = 0; j < VPL; j++) v += lrelu(hlv[j] + hrv[j]) * attv[j];
#pragma unroll
        for (int t = 1; t < LPH; t <<= 1) v += __shfl_xor(v, t, 64);
        // single-exp online softmax update
        float d = v - m;
        bool up = d > 0.f;
        float e1f = __expf(-fabsf(d));   // first edge: d=inf -> e1f=0
        float sc = up ? e1f : 1.f;
        float p  = up ? 1.f : e1f;
        m = up ? v : m;
        s = fmaf(s, sc, p);
#pragma unroll
        for (int j = 0; j < VPL; j++) acc[j] = fmaf(acc[j], sc, p * hlv[j]);
    }
    float inv = 1.f / (s + 1e-16f);
    float dnorm = inv / fmaxf((float)(e1 - e0), 1.f);
#pragma unroll
    for (int j = 0; j < VPL; j++)
        out[(size_t)w * outStride + outOfs + l * VPL + j] =
            acc[j] * dnorm + bias[l * VPL + j];
}

__global__ __launch_bounds__(256) void copy_col0(const float* __restrict__ zstd,
                                                 float* __restrict__ xA, int N) {
    for (int i = blockIdx.x * blockDim.x + threadIdx.x; i < N;
         i += gridDim.x * blockDim.x)
        xA[(size_t)i * 257] = zstd[i];
}

// ----------- BN stats, row-parallel: coalesced partial sums + atomics ------
// sums[0..F) = sum, sums[F..2F) = sumsq. Must be zeroed before launch.
__global__ __launch_bounds__(256) void bn_partial(
    const float* __restrict__ x, int Nrows, int F, float* __restrict__ sums) {
    const int t = threadIdx.x;
    if (F == 64) {
        int col = t & 63, rofs = t >> 6;
        float s1 = 0.f, s2 = 0.f;
        for (int r0 = blockIdx.x * 8; r0 < Nrows; r0 += gridDim.x * 8) {
#pragma unroll
            for (int u = 0; u < 2; u++) {
                int r = r0 + u * 4 + rofs;
                if (r < Nrows) {
                    float v = x[(size_t)r * 64 + col];
                    s1 += v; s2 += v * v;
                }
            }
        }
        atomicAdd(&sums[col], s1);
        atomicAdd(&sums[64 + col], s2);
    } else {
        const bool extra = (F > 256) && (t < F - 256);
        float a1 = 0.f, a2 = 0.f, b1 = 0.f, b2 = 0.f;
        for (int r0 = blockIdx.x * 2; r0 < Nrows; r0 += gridDim.x * 2) {
#pragma unroll
            for (int u = 0; u < 2; u++) {
                int r = r0 + u;
                if (r < Nrows) {
                    const float* row = x + (size_t)r * F;
                    float v = row[t];
                    a1 += v; a2 += v * v;
                    if (extra) {
                        float q = row[t + 256];
                        b1 += q; b2 += q * q;
                    }
                }
            }
        }
        atomicAdd(&sums[t], a1);
        atomicAdd(&sums[F + t], a2);
        if (extra) {
            atomicAdd(&sums[t + 256], b1);
            atomicAdd(&sums[F + t + 256], b2);
        }
    }
}

__global__ __launch_bounds__(256) void bn_finalize(
    const float* __restrict__ sums, int Nrows, int F,
    float* __restrict__ mean, float* __restrict__ istd) {
    for (int t = threadIdx.x; t < F; t += 256) {
        float mu = sums[t] / Nrows;
        float var = sums[F + t] / Nrows - mu * mu;
        mean[t] = mu;
        istd[t] = rsqrtf(fmaxf(var, 0.f) + 1e-5f);
    }
}

// y[i] = dot64(hid[i], W2) + b2
__global__ __launch_bounds__(256) void dot_w2(const float* __restrict__ hid,
                                              const float* __restrict__ W2,
                                              const float* __restrict__ b2,
                                              float* __restrict__ y, int N) {
    int w = blockIdx.x * (blockDim.x >> 6) + (threadIdx.x >> 6);
    int l = threadIdx.x & 63;
    if (w >= N) return;
    float v = hid[(size_t)w * 64 + l] * W2[l];
#pragma unroll
    for (int m = 1; m < 64; m <<= 1) v += __shfl_xor(v, m, 64);
    if (l == 0) y[w] = v + b2[0];
}

// ---------------------------------------------------------------------------
extern "C" void kernel_launch(void* const* d_in, const int* in_sizes, int n_in,
                              void* d_out, int out_size, void* d_ws, size_t ws_size,
                              hipStream_t stream) {
    const float* xl   = (const float*)d_in[0];
    const float* xh   = (const float*)d_in[1];
    const float* zstd = (const float*)d_in[2];
    const int* si_lh  = (const int*)d_in[3];
    const int* di_lh  = (const int*)d_in[4];
    const int* si_hh  = (const int*)d_in[5];
    const int* di_hh  = (const int*)d_in[6];
    int a = 7;
    const float *d_Wl = (const float*)d_in[a++], *d_bl = (const float*)d_in[a++],
                *d_Wr = (const float*)d_in[a++], *d_br = (const float*)d_in[a++],
                *d_att = (const float*)d_in[a++], *d_b = (const float*)d_in[a++];
    const float *p1_Wl = (const float*)d_in[a++], *p1_bl = (const float*)d_in[a++],
                *p1_Wr = (const float*)d_in[a++], *p1_br = (const float*)d_in[a++],
                *p1_att = (const float*)d_in[a++], *p1_b = (const float*)d_in[a++];
    const float *p2_Wl = (const float*)d_in[a++], *p2_bl = (const float*)d_in[a++],
                *p2_Wr = (const float*)d_in[a++], *p2_br = (const float*)d_in[a++],
                *p2_att = (const float*)d_in[a++], *p2_b = (const float*)d_in[a++];
    const float *p3_Wl = (const float*)d_in[a++], *p3_bl = (const float*)d_in[a++],
                *p3_Wr = (const float*)d_in[a++], *p3_br = (const float*)d_in[a++],
                *p3_att = (const float*)d_in[a++], *p3_b = (const float*)d_in[a++];
    const float *bn0_g = (const float*)d_in[a++], *bn0_b = (const float*)d_in[a++],
                *bn1_g = (const float*)d_in[a++], *bn1_b = (const float*)d_in[a++],
                *bn2_g = (const float*)d_in[a++], *bn2_b = (const float*)d_in[a++],
                *bn3_g = (const float*)d_in[a++], *bn3_b = (const float*)d_in[a++];
    const float *pr_W1 = (const float*)d_in[a++], *pr_b1 = (const float*)d_in[a++],
                *pr_W2 = (const float*)d_in[a++], *pr_b2 = (const float*)d_in[a++];
    float* y = (float*)d_out;

    const int N = N_HIGH;
    const int NMT = 3125;           // 50000/16
    const int NB = (N + 1023) / 1024;   // scan blocks = 49
    // ---- workspace layout ----
    float* ws = (float*)d_ws;
    float* xA = ws;                           // 50000*257 f32 (also hosts Af)
    float* xB = xA + (size_t)N * 257;         // 50000*256 f32 (also hosts Af)
    float* hl = xB + (size_t)N * 256;         // 50000*256 f32 (bf16 actually used)
    float* hr = hl + (size_t)N * 256;         // 50000*256 f32 (bf16 actually used)
    bf16x8* xl_f = (bf16x8*)(hr + (size_t)N * 256);   // 320*4*64 frags
    bf16x8* wf_d   = xl_f + 320 * 4 * 64;     // 16*4*64
    bf16x8* wf_p1l = wf_d + 16 * 4 * 64;      // 16*9*64
    bf16x8* wf_p1r = wf_p1l + 16 * 9 * 64;
    bf16x8* wf_p2l = wf_p1r + 16 * 9 * 64;    // 16*8*64
    bf16x8* wf_p2r = wf_p2l + 16 * 8 * 64;
    bf16x8* wf_p3l = wf_p2r + 16 * 8 * 64;    // 4*8*64
    bf16x8* wf_p3r = wf_p3l + 4 * 8 * 64;
    bf16x8* wf_pr1 = wf_p3r + 4 * 8 * 64;     // 4*2*64
    float* bnm = (float*)(wf_pr1 + 4 * 2 * 64);  // 257
    float* bni = bnm + 257;                   // 257
    float* bsum = bni + 257;                  // 514 (sum | sumsq)
    int* bscan  = (int*)(bsum + 514);         // 256 (scan block sums)
    int* itmp   = bscan + 256;                // 50000
    int* rp_lh  = itmp + N;                   // 50001
    int* rp_hh  = rp_lh + (N + 1);            // 50001
    int* cur    = rp_hh + (N + 1);            // 50000
    int* csr_lh = cur + N;                    // 200000
    int* csr_hh = csr_lh + E_LH;              // 450000
    int* src2   = csr_hh + E2;                // 450000
    int* dst2   = src2 + E2;                  // 450000
    size_t need = (size_t)((char*)(dst2 + E2) - (char*)ws);
    if (ws_size < need) return;
    bf16x8* AfB = (bf16x8*)xB;   // A-frags overlaying xB (while xB dead)
    bf16x8* AfA = (bf16x8*)xA;   // A-frags overlaying xA (while xA dead)
    unsigned short* hl16 = (unsigned short*)hl;
    unsigned short* hr16 = (unsigned short*)hr;

    dim3 blk(256);
    auto wgrid = [](int E) { return dim3((E + 3) / 4); };
    auto egrid = [](size_t total) {
        size_t g = (total + 255) / 256;
        return dim3((unsigned)(g > 2048 ? 2048 : g));
    };
    auto bn_run = [&](const float* x, int F, float* mean, float* istd) {
        hipMemsetAsync(bsum, 0, 2 * (size_t)F * sizeof(float), stream);
        bn_partial<<<dim3(512), blk, 0, stream>>>(x, N, F, bsum);
        bn_finalize<<<dim3(1), blk, 0, stream>>>(bsum, N, F, mean, istd);
    };
    auto exscan_run = [&](const int* cnt, int* off) {
        scan_partial<<<dim3(NB), blk, 0, stream>>>(cnt, off, bscan, N);
        scan_bsums<<<dim3(1), blk, 0, stream>>>(bscan, NB, off, N);
        scan_add<<<dim3(NB), blk, 0, stream>>>(off, bscan, N);
    };

    // ===================== weight fragment transforms =======================
    wt_frag<<<dim3(16), blk, 0, stream>>>(d_Wl, 125, 256, wf_d, 16, 4);
    wt_frag<<<dim3(36), blk, 0, stream>>>(p1_Wl, 257, 256, wf_p1l, 16, 9);
    wt_frag<<<dim3(36), blk, 0, stream>>>(p1_Wr, 257, 256, wf_p1r, 16, 9);
    wt_frag<<<dim3(32), blk, 0, stream>>>(p2_Wl, 256, 256, wf_p2l, 16, 8);
    wt_frag<<<dim3(32), blk, 0, stream>>>(p2_Wr, 256, 256, wf_p2r, 16, 8);
    wt_frag<<<dim3(8),  blk, 0, stream>>>(p3_Wl, 256, 64, wf_p3l, 4, 8);
    wt_frag<<<dim3(8),  blk, 0, stream>>>(p3_Wr, 256, 64, wf_p3r, 4, 8);
    wt_frag<<<dim3(2),  blk, 0, stream>>>(pr_W1, 64, 64, wf_pr1, 4, 2);
    cast_frag<<<dim3(320), blk, 0, stream>>>(xl, N_LOW, 125, xl_f, 320, 4);

    // ===================== CSR builds =======================================
    hipMemsetAsync(itmp, 0, (size_t)N * sizeof(int), stream);
    hist_dst<<<egrid(E_LH), blk, 0, stream>>>(di_lh, itmp, E_LH);
    exscan_run(itmp, rp_lh);
    hipMemcpyAsync(cur, rp_lh, (size_t)N * sizeof(int), hipMemcpyDeviceToDevice, stream);
    scatter_csr<<<egrid(E_LH), blk, 0, stream>>>(si_lh, di_lh, cur, csr_lh, E_LH);
    build_edges<<<egrid(E2), blk, 0, stream>>>(si_hh, di_hh, src2, dst2, E_HH, N);
    hipMemsetAsync(itmp, 0, (size_t)N * sizeof(int), stream);
    hist_dst<<<egrid(E2), blk, 0, stream>>>(dst2, itmp, E2);
    exscan_run(itmp, rp_hh);
    hipMemcpyAsync(cur, rp_hh, (size_t)N * sizeof(int), hipMemcpyDeviceToDevice, stream);
    scatter_csr<<<egrid(E2), blk, 0, stream>>>(src2, dst2, cur, csr_hh, E2);

    // ===================== d layer (low -> high, H=1, C=256) ================
    gemm_mfma<false, true><<<dim3(4, 40), blk, 0, stream>>>(xl_f, wf_d, d_bl, hl, N_LOW, 256, 4);
    outer_hr<<<egrid((size_t)N * 64), blk, 0, stream>>>(xh, d_Wr, d_br, hr16, N);
    gat_gather<1, 256><<<wgrid(N), blk, 0, stream>>>(hl16, hr16, rp_lh, csr_lh, d_att, d_b, xA, 257, 1, N);
    copy_col0<<<egrid(N), blk, 0, stream>>>(zstd, xA, N);

    // ===================== bn0 + frag cast ==================================
    bn_run(xA, 257, bnm, bni);
    bn_frag<false><<<dim3(2048), blk, 0, stream>>>(xA, N, 257, bnm, bni, bn0_g, bn0_b, AfB, NMT, 9);

    // ===================== p1 (H=4, C=64) ===================================
    gemm_mfma<false, true><<<dim3(4, 391), blk, 0, stream>>>(AfB, wf_p1l, p1_bl, hl, N, 256, 9);
    gemm_mfma<false, true><<<dim3(4, 391), blk, 0, stream>>>(AfB, wf_p1r, p1_br, hr, N, 256, 9);
    gat_gather<4, 64><<<wgrid(N), blk, 0, stream>>>(hl16, hr16, rp_hh, csr_hh, p1_att, p1_b, xB, 256, 0, N);
    bn_run(xB, 256, bnm, bni);
    bn_frag<true><<<dim3(2048), blk, 0, stream>>>(xB, N, 256, bnm, bni, bn1_g, bn1_b, AfA, NMT, 8);

    // ===================== p2 (H=4, C=64) ===================================
    gemm_mfma<false, true><<<dim3(4, 391), blk, 0, stream>>>(AfA, wf_p2l, p2_bl, hl, N, 256, 8);
    gemm_mfma<false, true><<<dim3(4, 391), blk, 0, stream>>>(AfA, wf_p2r, p2_br, hr, N, 256, 8);
    gat_gather<4, 64><<<wgrid(N), blk, 0, stream>>>(hl16, hr16, rp_hh, csr_hh, p2_att, p2_b, xA, 256, 0, N);
    bn_run(xA, 256, bnm, bni);
    bn_frag<true><<<dim3(2048), blk, 0, stream>>>(xA, N, 256, bnm, bni, bn2_g, bn2_b, AfB, NMT, 8);

    // ===================== p3 (H=1, C=64) ===================================
    gemm_mfma<false, true><<<dim3(1, 391), blk, 0, stream>>>(AfB, wf_p3l, p3_bl, hl, N, 64, 8);
    gemm_mfma<false, true><<<dim3(1, 391), blk, 0, stream>>>(AfB, wf_p3r, p3_br, hr, N, 64, 8);
    gat_gather<1, 64><<<wgrid(N), blk, 0, stream>>>(hl16, hr16, rp_hh, csr_hh, p3_att, p3_b, xB, 64, 0, N);
    bn_run(xB, 64, bnm, bni);
    bn_frag<true><<<dim3(2048), blk, 0, stream>>>(xB, N, 64, bnm, bni, bn3_g, bn3_b, AfA, NMT, 2);

    // ===================== predictor MLP ====================================
    gemm_mfma<true, false><<<dim3(1, 391), blk, 0, stream>>>(AfA, wf_pr1, pr_b1, hl, N, 64, 2);
    dot_w2<<<wgrid(N), blk, 0, stream>>>(hl, pr_W2, pr_b2, y, N);
}